// Round 7
// baseline (655.016 us; speedup 1.0000x reference)
//
#include <hip/hip_runtime.h>
#include <stdint.h>

typedef __attribute__((ext_vector_type(8))) short bf16x8;
typedef __attribute__((ext_vector_type(8))) _Float16 f16x8;
typedef __attribute__((ext_vector_type(4))) float f32x4;
typedef __attribute__((ext_vector_type(4))) unsigned short us4;
typedef __attribute__((ext_vector_type(8))) unsigned short us8;
typedef unsigned short u16;

#define DEVI static __device__ __forceinline__

#define Bb 4
#define Tt 4096
#define Cch 512
#define DFFd 2048
#define Mrows (Bb*Tt)

DEVI u16 f2bf(float f){
  union{float f;unsigned u;} v; v.f = f;
  unsigned r = v.u + 0x7FFFu + ((v.u >> 16) & 1u);
  return (u16)(r >> 16);
}
DEVI float bf2f(u16 h){
  union{unsigned u;float f;} v; v.u = (unsigned)h << 16; return v.f;
}
DEVI u16 f2h(float f){
  union{_Float16 h; u16 u;} v; v.h = (_Float16)f; return v.u;
}
// packed-triangular pane offset (f32 elements): sum_{j<q}(j+1)*128*128
DEVI size_t PANE(int q){ return (size_t)8192 * (size_t)(q*(q+1)); }

DEVI void gload16(const void* g, void* l){
  __builtin_amdgcn_global_load_lds((const __attribute__((address_space(1))) unsigned int*)g,
                                   (__attribute__((address_space(3))) unsigned int*)l, 16, 0, 0);
}

// ---------------- split cast f32 -> (hi, lo) bf16 ----------------
__global__ void k_split_cast(const float* __restrict__ in, u16* __restrict__ hi,
                             u16* __restrict__ lo, int n){
  int i = (blockIdx.x * blockDim.x + threadIdx.x) * 4;
  if(i < n){
    float4 f = *(const float4*)(in + i);
    us4 h, l;
    h.x = f2bf(f.x); l.x = f2bf(f.x - bf2f(h.x));
    h.y = f2bf(f.y); l.y = f2bf(f.y - bf2f(h.y));
    h.z = f2bf(f.z); l.z = f2bf(f.z - bf2f(h.z));
    h.w = f2bf(f.w); l.w = f2bf(f.w - bf2f(h.w));
    *(us4*)(hi + i) = h; *(us4*)(lo + i) = l;
  }
}

// ------------- transpose-cast f32 -> bf16 (plain) -------------
__global__ void k_transpose_f32_bf16(const float* __restrict__ in, u16* __restrict__ out,
                                     int inStride, int outStride){
  __shared__ float tile[32][33];
  int c0 = blockIdx.x * 32, r0 = blockIdx.y * 32;
  int tx = threadIdx.x, ty = threadIdx.y; // (32,8)
  #pragma unroll
  for(int j = 0; j < 4; j++)
    tile[ty + 8*j][tx] = in[(size_t)(r0 + ty + 8*j) * inStride + c0 + tx];
  __syncthreads();
  #pragma unroll
  for(int j = 0; j < 4; j++)
    out[(size_t)(c0 + ty + 8*j) * outStride + r0 + tx] = f2bf(tile[tx][ty + 8*j]);
}

// ------------- transpose-cast f32 -> (hi,lo) bf16 -------------
__global__ void k_transpose_split(const float* __restrict__ in, u16* __restrict__ oh,
                                  u16* __restrict__ ol, int inStride, int outStride){
  __shared__ float tile[32][33];
  int c0 = blockIdx.x * 32, r0 = blockIdx.y * 32;
  int tx = threadIdx.x, ty = threadIdx.y;
  #pragma unroll
  for(int j = 0; j < 4; j++)
    tile[ty + 8*j][tx] = in[(size_t)(r0 + ty + 8*j) * inStride + c0 + tx];
  __syncthreads();
  #pragma unroll
  for(int j = 0; j < 4; j++){
    float x = tile[tx][ty + 8*j];
    u16 h = f2bf(x);
    size_t o = (size_t)(c0 + ty + 8*j) * outStride + r0 + tx;
    oh[o] = h; ol[o] = f2bf(x - bf2f(h));
  }
}

// ---------------- split-precision GEMM core (bf16 hi/lo, 3 MFMA) ----------------
DEVI void core_split(const u16* __restrict__ Ah, const u16* __restrict__ Al,
                     const u16* __restrict__ Bh, const u16* __restrict__ Bl,
                     int lda, int ldb, int K,
                     u16* Ash, u16* Asl, u16* Bsh, u16* Bsl,
                     f32x4 (&acc)[4][4]){
  const int t = threadIdx.x;
  const int lane = t & 63, w = t >> 6;
  const int l15 = lane & 15, l4 = lane >> 4;
  const int wr = (w >> 1) * 64, wc = (w & 1) * 64;
  for(int kt = 0; kt < K; kt += 32){
    __syncthreads();
    #pragma unroll
    for(int i = 0; i < 2; i++){
      int row = i*64 + (t >> 2);
      int ce  = (t & 3) * 8;
      size_t ao = (size_t)row * lda + kt + ce;
      size_t bo = (size_t)row * ldb + kt + ce;
      gload16(Ah + ao, (char*)Ash + i*4096 + t*16);
      gload16(Al + ao, (char*)Asl + i*4096 + t*16);
      gload16(Bh + bo, (char*)Bsh + i*4096 + t*16);
      gload16(Bl + bo, (char*)Bsl + i*4096 + t*16);
    }
    __syncthreads();
    bf16x8 ah[4], al[4], bh[4], bl[4];
    #pragma unroll
    for(int mi = 0; mi < 4; mi++){
      ah[mi] = *(const bf16x8*)((const char*)Ash + (wr + mi*16 + l15)*64 + l4*16);
      al[mi] = *(const bf16x8*)((const char*)Asl + (wr + mi*16 + l15)*64 + l4*16);
    }
    #pragma unroll
    for(int ni = 0; ni < 4; ni++){
      bh[ni] = *(const bf16x8*)((const char*)Bsh + (wc + ni*16 + l15)*64 + l4*16);
      bl[ni] = *(const bf16x8*)((const char*)Bsl + (wc + ni*16 + l15)*64 + l4*16);
    }
    #pragma unroll
    for(int mi = 0; mi < 4; mi++)
      #pragma unroll
      for(int ni = 0; ni < 4; ni++){
        acc[mi][ni] = __builtin_amdgcn_mfma_f32_16x16x32_bf16(ah[mi], bh[ni], acc[mi][ni], 0, 0, 0);
        acc[mi][ni] = __builtin_amdgcn_mfma_f32_16x16x32_bf16(ah[mi], bl[ni], acc[mi][ni], 0, 0, 0);
        acc[mi][ni] = __builtin_amdgcn_mfma_f32_16x16x32_bf16(al[mi], bh[ni], acc[mi][ni], 0, 0, 0);
      }
  }
}

// ---------------- QK projection, split precision, single f16 output [M][1024] ----------------
__global__ __launch_bounds__(256) void k_qk_split(const u16* __restrict__ Xh, const u16* __restrict__ Xl,
                                                  const u16* __restrict__ Wh, const u16* __restrict__ Wl,
                                                  u16* __restrict__ QK){
  __shared__ u16 Ash[4096], Asl[4096], Bsh[4096], Bsl[4096];
  const int bm = blockIdx.x * 128, bn = blockIdx.y * 128;
  f32x4 acc[4][4] = {};
  core_split(Xh + (size_t)bm*512, Xl + (size_t)bm*512,
             Wh + (size_t)bn*512, Wl + (size_t)bn*512,
             512, 512, 512, Ash, Asl, Bsh, Bsl, acc);
  const int t = threadIdx.x, lane = t & 63, w = t >> 6;
  const int l15 = lane & 15, l4 = lane >> 4;
  const int wr = (w >> 1) * 64, wc = (w & 1) * 64;
  #pragma unroll
  for(int mi = 0; mi < 4; mi++)
    #pragma unroll
    for(int ni = 0; ni < 4; ni++){
      int col = bn + wc + ni*16 + l15;
      #pragma unroll
      for(int r = 0; r < 4; r++){
        int row = bm + wr + mi*16 + l4*4 + r;
        QK[(size_t)row * 1024 + col] = f2h(acc[mi][ni][r]);
      }
    }
}

// ---------------- f16 GEMM core (single MFMA) ----------------
DEVI void core_f16(const u16* __restrict__ A, const u16* __restrict__ B,
                   int lda, int ldb, int K, u16* As, u16* Bs, f32x4 (&acc)[4][4]){
  const int t = threadIdx.x;
  const int lane = t & 63, w = t >> 6;
  const int l15 = lane & 15, l4 = lane >> 4;
  const int wr = (w >> 1) * 64, wc = (w & 1) * 64;
  for(int kt = 0; kt < K; kt += 32){
    __syncthreads();
    #pragma unroll
    for(int i = 0; i < 2; i++){
      int row = i*64 + (t >> 2);
      int ce  = (t & 3) * 8;
      gload16(A + (size_t)row * lda + kt + ce, (char*)As + i*4096 + t*16);
      gload16(B + (size_t)row * ldb + kt + ce, (char*)Bs + i*4096 + t*16);
    }
    __syncthreads();
    f16x8 af[4], bfr[4];
    #pragma unroll
    for(int mi = 0; mi < 4; mi++)
      af[mi] = *(const f16x8*)((const char*)As + (wr + mi*16 + l15)*64 + l4*16);
    #pragma unroll
    for(int ni = 0; ni < 4; ni++)
      bfr[ni] = *(const f16x8*)((const char*)Bs + (wc + ni*16 + l15)*64 + l4*16);
    #pragma unroll
    for(int mi = 0; mi < 4; mi++)
      #pragma unroll
      for(int ni = 0; ni < 4; ni++)
        acc[mi][ni] = __builtin_amdgcn_mfma_f32_16x16x32_f16(af[mi], bfr[ni], acc[mi][ni], 0, 0, 0);
  }
}

// ---------------- causal score GEMM (one batch): f32 S + per-tile softmax stats ----------------
__global__ __launch_bounds__(256) void k_score(const u16* __restrict__ QKb,
                                               float* __restrict__ Sp,
                                               float2* __restrict__ Sstats){
  const int kt = blockIdx.x, qt = blockIdx.y;
  if(kt > qt) return;
  __shared__ u16 As[4096], Bs[4096];
  __shared__ float2 SmL[4][64];
  const u16* A = QKb + (size_t)(qt*128) * 1024;        // q rows
  const u16* B = QKb + (size_t)(kt*128) * 1024 + 512;  // k rows
  f32x4 acc[4][4] = {};
  core_f16(A, B, 1024, 1024, 512, As, Bs, acc);
  const int t = threadIdx.x, lane = t & 63, w = t >> 6;
  const int l15 = lane & 15, l4 = lane >> 4;
  const int wr = (w >> 1) * 64, wc = (w & 1) * 64;
  const int ldc = (qt + 1) * 128;
  const bool diag = (kt == qt);
  const float NI = -__builtin_inff();
  // causal mask into acc
  if(diag){
    #pragma unroll
    for(int mi = 0; mi < 4; mi++)
      #pragma unroll
      for(int ni = 0; ni < 4; ni++){
        int cl = wc + ni*16 + l15;
        #pragma unroll
        for(int r = 0; r < 4; r++)
          if(cl > wr + mi*16 + l4*4 + r) acc[mi][ni][r] = NI;
      }
  }
  // store S tile (f32)
  float* C = Sp + PANE(qt) + (size_t)kt*128;
  #pragma unroll
  for(int mi = 0; mi < 4; mi++)
    #pragma unroll
    for(int ni = 0; ni < 4; ni++){
      int cl = wc + ni*16 + l15;
      #pragma unroll
      for(int r = 0; r < 4; r++)
        C[(size_t)(wr + mi*16 + l4*4 + r) * ldc + cl] = acc[mi][ni][r];
    }
  // per-row partial stats over this tile's 128 cols (two wave-halves combined via LDS)
  #pragma unroll
  for(int mi = 0; mi < 4; mi++)
    #pragma unroll
    for(int r = 0; r < 4; r++){
      float mx = fmaxf(fmaxf(acc[mi][0][r], acc[mi][1][r]), fmaxf(acc[mi][2][r], acc[mi][3][r]));
      mx = fmaxf(mx, __shfl_xor(mx, 1));
      mx = fmaxf(mx, __shfl_xor(mx, 2));
      mx = fmaxf(mx, __shfl_xor(mx, 4));
      mx = fmaxf(mx, __shfl_xor(mx, 8));
      float ls = 0.f;
      if(mx > -1e38f){
        #pragma unroll
        for(int ni = 0; ni < 4; ni++) ls += __expf(acc[mi][ni][r] - mx);
      }
      ls += __shfl_xor(ls, 1);
      ls += __shfl_xor(ls, 2);
      ls += __shfl_xor(ls, 4);
      ls += __shfl_xor(ls, 8);
      if(l15 == 0){ SmL[w][mi*16 + l4*4 + r] = (float2){mx, ls}; }
    }
  __syncthreads();
  if(!(w & 1)){
    float2 a = SmL[w][lane];
    float2 b = SmL[w + 1][lane];
    float M = fmaxf(a.x, b.x);
    float Ls = 0.f;
    if(a.x > -1e38f) Ls += a.y * __expf(a.x - M);
    if(b.x > -1e38f) Ls += b.y * __expf(b.x - M);
    Sstats[(qt*32 + kt)*128 + wr + lane] = (float2){M, Ls};
  }
}

// ---------------- PV GEMM with fused softmax (one batch): exp-on-stage, atomic f32 out ----------------
__global__ __launch_bounds__(256) void k_pv(const float* __restrict__ Sp,
                                            const float2* __restrict__ Sstats,
                                            const u16* __restrict__ Vtb,
                                            float* __restrict__ NVacc){
  const int nc = blockIdx.x, qt = blockIdx.y, kc = blockIdx.z;
  const int L = (qt + 1) * 128;
  const int k0 = kc * 1024;
  if(k0 >= L) return;
  const int kLen = (L - k0) < 1024 ? (L - k0) : 1024;
  __shared__ u16 As[128 * 40];   // padded stride 40 u16 (80B, 16B-aligned, ~conflict-free)
  __shared__ u16 Bs[4096];
  __shared__ float rsM[128], rsI[128];
  const int t = threadIdx.x, lane = t & 63, w = t >> 6;
  const int l15 = lane & 15, l4 = lane >> 4;
  const int wr = (w >> 1) * 64, wc = (w & 1) * 64;
  // combine per-tile stats -> per-row (M, 1/L)
  if(t < 128){
    float M = -__builtin_inff();
    for(int kk = 0; kk <= qt; kk++) M = fmaxf(M, Sstats[(qt*32 + kk)*128 + t].x);
    float Ls = 0.f;
    for(int kk = 0; kk <= qt; kk++){
      float2 s = Sstats[(qt*32 + kk)*128 + t];
      if(s.x > -1e38f) Ls += s.y * __expf(s.x - M);
    }
    rsM[t] = M; rsI[t] = 1.f / Ls;
  }
  __syncthreads();
  const int arow = t >> 1, acg = (t & 1) * 16;
  const float aM = rsM[arow], aI = rsI[arow];
  const float* Sb = Sp + PANE(qt) + (size_t)arow * L + k0 + acg;
  f32x4 acc[4][4] = {};
  for(int kt = 0; kt < kLen; kt += 32){
    __syncthreads();
    #pragma unroll
    for(int i = 0; i < 2; i++){
      int row = i*64 + (t >> 2);
      int ce  = (t & 3) * 8;
      gload16(Vtb + (size_t)(nc*128 + row) * Tt + k0 + kt + ce, (char*)Bs + i*4096 + t*16);
    }
    {
      const float* sp = Sb + kt;
      u16 tmp[16];
      #pragma unroll
      for(int j = 0; j < 16; j += 4){
        float4 f = *(const float4*)(sp + j);
        tmp[j]   = f2bf(__expf(f.x - aM) * aI);
        tmp[j+1] = f2bf(__expf(f.y - aM) * aI);
        tmp[j+2] = f2bf(__expf(f.z - aM) * aI);
        tmp[j+3] = f2bf(__expf(f.w - aM) * aI);
      }
      u16* dst = As + arow*40 + acg;
      *(us8*)dst = *(const us8*)tmp;
      *(us8*)(dst + 8) = *(const us8*)(tmp + 8);
    }
    __syncthreads();
    bf16x8 af[4], bfr[4];
    #pragma unroll
    for(int mi = 0; mi < 4; mi++)
      af[mi] = *(const bf16x8*)((const char*)As + (wr + mi*16 + l15)*80 + l4*16);
    #pragma unroll
    for(int ni = 0; ni < 4; ni++)
      bfr[ni] = *(const bf16x8*)((const char*)Bs + (wc + ni*16 + l15)*64 + l4*16);
    #pragma unroll
    for(int mi = 0; mi < 4; mi++)
      #pragma unroll
      for(int ni = 0; ni < 4; ni++)
        acc[mi][ni] = __builtin_amdgcn_mfma_f32_16x16x32_bf16(af[mi], bfr[ni], acc[mi][ni], 0, 0, 0);
  }
  float* Cb = NVacc + (size_t)(qt*128) * Cch + nc*128;
  #pragma unroll
  for(int mi = 0; mi < 4; mi++)
    #pragma unroll
    for(int ni = 0; ni < 4; ni++){
      int cl = wc + ni*16 + l15;
      #pragma unroll
      for(int r = 0; r < 4; r++){
        int rl = wr + mi*16 + l4*4 + r;
        atomicAdd(&Cb[(size_t)rl * Cch + cl], acc[mi][ni][r]);
      }
    }
}

// ---------------- plain bf16 GEMM core ----------------
DEVI void core_plain(const u16* __restrict__ A, const u16* __restrict__ B,
                     int lda, int ldb, int K, u16* As, u16* Bs, f32x4 (&acc)[4][4]){
  const int t = threadIdx.x;
  const int lane = t & 63, w = t >> 6;
  const int l15 = lane & 15, l4 = lane >> 4;
  const int wr = (w >> 1) * 64, wc = (w & 1) * 64;
  for(int kt = 0; kt < K; kt += 32){
    __syncthreads();
    #pragma unroll
    for(int i = 0; i < 2; i++){
      int row = i*64 + (t >> 2);
      int ce  = (t & 3) * 8;
      gload16(A + (size_t)row * lda + kt + ce, (char*)As + i*4096 + t*16);
      gload16(B + (size_t)row * ldb + kt + ce, (char*)Bs + i*4096 + t*16);
    }
    __syncthreads();
    bf16x8 af[4], bfr[4];
    #pragma unroll
    for(int mi = 0; mi < 4; mi++)
      af[mi] = *(const bf16x8*)((const char*)As + (wr + mi*16 + l15)*64 + l4*16);
    #pragma unroll
    for(int ni = 0; ni < 4; ni++)
      bfr[ni] = *(const bf16x8*)((const char*)Bs + (wc + ni*16 + l15)*64 + l4*16);
    #pragma unroll
    for(int mi = 0; mi < 4; mi++)
      #pragma unroll
      for(int ni = 0; ni < 4; ni++)
        acc[mi][ni] = __builtin_amdgcn_mfma_f32_16x16x32_bf16(af[mi], bfr[ni], acc[mi][ni], 0, 0, 0);
  }
}

// ---------------- V projection GEMM, writes transposed Vt ----------------
__global__ __launch_bounds__(256) void k_vproj(const u16* __restrict__ A,
                                               const u16* __restrict__ Bt,
                                               u16* __restrict__ Vt){
  __shared__ u16 As[4096], Bs[4096];
  const int bm = blockIdx.x * 128, bn = blockIdx.y * 128;
  f32x4 acc[4][4] = {};
  core_plain(A + (size_t)bm*512, Bt + (size_t)bn*512, 512, 512, 512, As, Bs, acc);
  const int t = threadIdx.x, lane = t & 63, w = t >> 6;
  const int l15 = lane & 15, l4 = lane >> 4;
  const int wr = (w >> 1) * 64, wc = (w & 1) * 64;
  #pragma unroll
  for(int mi = 0; mi < 4; mi++)
    #pragma unroll
    for(int ni = 0; ni < 4; ni++){
      int col = bn + wc + ni*16 + l15;
      #pragma unroll
      for(int r = 0; r < 4; r++){
        int row = bm + wr + mi*16 + l4*4 + r;
        int b = row >> 12, tq = row & 4095;
        Vt[((size_t)b * Cch + col) * Tt + tq] = f2bf(acc[mi][ni][r]);
      }
    }
}

// ---------------- FFN1: A from f32 (reg-staged), +bias, relu, bf16 out ----------------
__global__ __launch_bounds__(256) void k_ffn1(const float* __restrict__ A,
                                              const u16* __restrict__ Bt,
                                              u16* __restrict__ Hout,
                                              const float* __restrict__ bias){
  __shared__ u16 As[128 * 40];
  __shared__ u16 Bs[4096];
  const int bm = blockIdx.x * 128, bn = blockIdx.y * 128;
  const int t = threadIdx.x, lane = t & 63, w = t >> 6;
  const int l15 = lane & 15, l4 = lane >> 4;
  const int wr = (w >> 1) * 64, wc = (w & 1) * 64;
  const int arow = t >> 1, acg = (t & 1) * 16;
  const float* ap0 = A + (size_t)(bm + arow) * 512 + acg;
  f32x4 acc[4][4] = {};
  for(int kt = 0; kt < 512; kt += 32){
    __syncthreads();
    #pragma unroll
    for(int i = 0; i < 2; i++){
      int row = i*64 + (t >> 2);
      int ce  = (t & 3) * 8;
      gload16(Bt + (size_t)(bn + row) * 512 + kt + ce, (char*)Bs + i*4096 + t*16);
    }
    {
      const float* sp = ap0 + kt;
      u16 tmp[16];
      #pragma unroll
      for(int j = 0; j < 16; j += 4){
        float4 f = *(const float4*)(sp + j);
        tmp[j]   = f2bf(f.x);
        tmp[j+1] = f2bf(f.y);
        tmp[j+2] = f2bf(f.z);
        tmp[j+3] = f2bf(f.w);
      }
      u16* dst = As + arow*40 + acg;
      *(us8*)dst = *(const us8*)tmp;
      *(us8*)(dst + 8) = *(const us8*)(tmp + 8);
    }
    __syncthreads();
    bf16x8 af[4], bfr[4];
    #pragma unroll
    for(int mi = 0; mi < 4; mi++)
      af[mi] = *(const bf16x8*)((const char*)As + (wr + mi*16 + l15)*80 + l4*16);
    #pragma unroll
    for(int ni = 0; ni < 4; ni++)
      bfr[ni] = *(const bf16x8*)((const char*)Bs + (wc + ni*16 + l15)*64 + l4*16);
    #pragma unroll
    for(int mi = 0; mi < 4; mi++)
      #pragma unroll
      for(int ni = 0; ni < 4; ni++)
        acc[mi][ni] = __builtin_amdgcn_mfma_f32_16x16x32_bf16(af[mi], bfr[ni], acc[mi][ni], 0, 0, 0);
  }
  #pragma unroll
  for(int mi = 0; mi < 4; mi++)
    #pragma unroll
    for(int ni = 0; ni < 4; ni++){
      int col = bn + wc + ni*16 + l15;
      float bv = bias[col];
      #pragma unroll
      for(int r = 0; r < 4; r++){
        int row = bm + wr + mi*16 + l4*4 + r;
        float v = acc[mi][ni][r] + bv;
        v = v > 0.f ? v : 0.f;
        Hout[(size_t)row * DFFd + col] = f2bf(v);
      }
    }
}

// ---------------- FFN2: split-K x2, atomicAdd f32 into pre-zeroed out ----------------
__global__ __launch_bounds__(256) void k_ffn2(const u16* __restrict__ A,
                                              const u16* __restrict__ Bt,
                                              float* __restrict__ out,
                                              const float* __restrict__ bias){
  __shared__ u16 As[4096], Bs[4096];
  const int bm = blockIdx.x * 128, bn = blockIdx.y * 128, kc = blockIdx.z;
  f32x4 acc[4][4] = {};
  core_plain(A + (size_t)bm*2048 + kc*1024, Bt + (size_t)bn*2048 + kc*1024,
             2048, 2048, 1024, As, Bs, acc);
  const int t = threadIdx.x, lane = t & 63, w = t >> 6;
  const int l15 = lane & 15, l4 = lane >> 4;
  const int wr = (w >> 1) * 64, wc = (w & 1) * 64;
  #pragma unroll
  for(int mi = 0; mi < 4; mi++)
    #pragma unroll
    for(int ni = 0; ni < 4; ni++){
      int col = bn + wc + ni*16 + l15;
      float bv = (kc == 0) ? bias[col] : 0.f;
      #pragma unroll
      for(int r = 0; r < 4; r++){
        int row = bm + wr + mi*16 + l4*4 + r;
        atomicAdd(&out[(size_t)row * Cch + col], acc[mi][ni][r] + bv);
      }
    }
}

// ---------------- zero util ----------------
__global__ void k_zero4(float* __restrict__ p, int n){
  int i = (blockIdx.x * blockDim.x + threadIdx.x) * 4;
  if(i < n) *(f32x4*)(p + i) = (f32x4){0.f,0.f,0.f,0.f};
}

// ---------------- launch ----------------
extern "C" void kernel_launch(void* const* d_in, const int* in_sizes, int n_in,
                              void* d_out, int out_size, void* d_ws, size_t ws_size,
                              hipStream_t stream){
  (void)in_sizes; (void)n_in; (void)out_size; (void)ws_size;
  const float* X  = (const float*)d_in[0];
  const float* Wq = (const float*)d_in[1];
  const float* Wk = (const float*)d_in[2];
  const float* Wv = (const float*)d_in[3];
  const float* W1 = (const float*)d_in[4];
  const float* b1 = (const float*)d_in[5];
  const float* W2 = (const float*)d_in[6];
  const float* b2 = (const float*)d_in[7];
  float* out = (float*)d_out;

  // workspace (MB offsets), peak ~157 MB:
  // [0,16) Xh            dead after projections  -> H [0,64) for FFN
  // [16,32) Xl           dead after projections
  // [32,64) QK f16       dead after last k_score
  // [64,80) Vt           dead after last k_pv
  // [80,114) NVacc f32   dead after k_ffn1
  // [114..121) weights
  // [121,155.6) Sp       per-batch pane buffer
  // [156,157) Sstats
  const size_t MB = 1024ull*1024ull;
  char* ws = (char*)d_ws;
  u16*    Xh     = (u16*)(ws + 0);
  u16*    H      = (u16*)(ws + 0);
  u16*    Xl     = (u16*)(ws + 16*MB);
  u16*    QK     = (u16*)(ws + 32*MB);
  u16*    Vt     = (u16*)(ws + 64*MB);
  float*  NVacc  = (float*)(ws + 80*MB);
  u16*    Wqkh   = (u16*)(ws + 114*MB);
  u16*    Wqkl   = (u16*)(ws + 115*MB);
  u16*    Wvt    = (u16*)(ws + 116*MB);
  u16*    W1t    = (u16*)(ws + 117*MB);
  u16*    W2t    = (u16*)(ws + 119*MB);
  float*  Sp     = (float*)(ws + 121*MB);
  float2* Sstats = (float2*)(ws + 156*MB);

  dim3 tb(32, 8);

  // 1. split-cast X; zero output (atomic FFN2 target)
  k_split_cast<<<Mrows*Cch/4/256, 256, 0, stream>>>(X, Xh, Xl, Mrows*Cch);
  k_zero4<<<Mrows*Cch/4/256, 256, 0, stream>>>(out, Mrows*Cch);

  // 2. weight transposes (Wq/Wk split, Wv/W1/W2 plain)
  k_transpose_split<<<dim3(16,16), tb, 0, stream>>>(Wq, Wqkh,           Wqkl,           512, 512);
  k_transpose_split<<<dim3(16,16), tb, 0, stream>>>(Wk, Wqkh + 512*512, Wqkl + 512*512, 512, 512);
  k_transpose_f32_bf16<<<dim3(16,16), tb, 0, stream>>>(Wv, Wvt, 512, 512);
  k_transpose_f32_bf16<<<dim3(64,16), tb, 0, stream>>>(W1, W1t, 2048, 512);
  k_transpose_f32_bf16<<<dim3(16,64), tb, 0, stream>>>(W2, W2t, 512, 2048);

  // 3. QK projection (split-bf16 compute, f16 store); V projection -> transposed Vt
  k_qk_split<<<dim3(128, 8), 256, 0, stream>>>(Xh, Xl, Wqkh, Wqkl, QK);
  k_vproj<<<dim3(128, 4), 256, 0, stream>>>(Xh, Wvt, Vt);

  // 4. attention: per-batch score(+stats) then softmax-fused PV (atomic into NVacc)
  k_zero4<<<Mrows*Cch/4/256, 256, 0, stream>>>(NVacc, Mrows*Cch);
  for(int b = 0; b < Bb; b++){
    k_score<<<dim3(32, 32), 256, 0, stream>>>(QK + (size_t)b*Tt*1024, Sp, Sstats);
    k_pv<<<dim3(4, 32, 4), 256, 0, stream>>>(Sp, Sstats, Vt + (size_t)b*Cch*Tt,
                                             NVacc + (size_t)b*Tt*Cch);
  }

  // 5. FFN (FFN1 reads f32 NVacc directly; FFN2 split-K atomic into zeroed out)
  k_ffn1<<<dim3(128, 16), 256, 0, stream>>>(NVacc, W1t, H, b1);
  k_ffn2<<<dim3(128, 4, 2), 256, 0, stream>>>(H, W2t, out, b2);
}

// Round 8
// 455.571 us; speedup vs baseline: 1.4378x; 1.4378x over previous
//
#include <hip/hip_runtime.h>
#include <stdint.h>

typedef __attribute__((ext_vector_type(8))) short bf16x8;
typedef __attribute__((ext_vector_type(8))) _Float16 f16x8;
typedef __attribute__((ext_vector_type(4))) float f32x4;
typedef __attribute__((ext_vector_type(4))) unsigned short us4;
typedef unsigned short u16;

#define DEVI static __device__ __forceinline__

#define Bb 4
#define Tt 4096
#define Cch 512
#define DFFd 2048
#define Mrows (Bb*Tt)
#define TRI 8650752ull   // f32 elements per packed causal pane = PANE(32)

DEVI u16 f2bf(float f){
  union{float f;unsigned u;} v; v.f = f;
  unsigned r = v.u + 0x7FFFu + ((v.u >> 16) & 1u);
  return (u16)(r >> 16);
}
DEVI float bf2f(u16 h){
  union{unsigned u;float f;} v; v.u = (unsigned)h << 16; return v.f;
}
DEVI u16 f2h(float f){
  union{_Float16 h; u16 u;} v; v.h = (_Float16)f; return v.u;
}
// packed-triangular pane offset (f32 elements): sum_{j<q}(j+1)*128*128
DEVI size_t PANE(int q){ return (size_t)8192 * (size_t)(q*(q+1)); }

DEVI void gload16(const void* g, void* l){
  __builtin_amdgcn_global_load_lds((const __attribute__((address_space(1))) unsigned int*)g,
                                   (__attribute__((address_space(3))) unsigned int*)l, 16, 0, 0);
}

// ---------------- split cast f32 -> (hi, lo) bf16 ----------------
__global__ void k_split_cast(const float* __restrict__ in, u16* __restrict__ hi,
                             u16* __restrict__ lo, int n){
  int i = (blockIdx.x * blockDim.x + threadIdx.x) * 4;
  if(i < n){
    float4 f = *(const float4*)(in + i);
    us4 h, l;
    h.x = f2bf(f.x); l.x = f2bf(f.x - bf2f(h.x));
    h.y = f2bf(f.y); l.y = f2bf(f.y - bf2f(h.y));
    h.z = f2bf(f.z); l.z = f2bf(f.z - bf2f(h.z));
    h.w = f2bf(f.w); l.w = f2bf(f.w - bf2f(h.w));
    *(us4*)(hi + i) = h; *(us4*)(lo + i) = l;
  }
}

// ------------- transpose-cast f32 -> bf16 (plain) -------------
__global__ void k_transpose_f32_bf16(const float* __restrict__ in, u16* __restrict__ out,
                                     int inStride, int outStride){
  __shared__ float tile[32][33];
  int c0 = blockIdx.x * 32, r0 = blockIdx.y * 32;
  int tx = threadIdx.x, ty = threadIdx.y; // (32,8)
  #pragma unroll
  for(int j = 0; j < 4; j++)
    tile[ty + 8*j][tx] = in[(size_t)(r0 + ty + 8*j) * inStride + c0 + tx];
  __syncthreads();
  #pragma unroll
  for(int j = 0; j < 4; j++)
    out[(size_t)(c0 + ty + 8*j) * outStride + r0 + tx] = f2bf(tile[tx][ty + 8*j]);
}

// ------------- transpose-cast f32 -> (hi,lo) bf16 -------------
__global__ void k_transpose_split(const float* __restrict__ in, u16* __restrict__ oh,
                                  u16* __restrict__ ol, int inStride, int outStride){
  __shared__ float tile[32][33];
  int c0 = blockIdx.x * 32, r0 = blockIdx.y * 32;
  int tx = threadIdx.x, ty = threadIdx.y;
  #pragma unroll
  for(int j = 0; j < 4; j++)
    tile[ty + 8*j][tx] = in[(size_t)(r0 + ty + 8*j) * inStride + c0 + tx];
  __syncthreads();
  #pragma unroll
  for(int j = 0; j < 4; j++){
    float x = tile[tx][ty + 8*j];
    u16 h = f2bf(x);
    size_t o = (size_t)(c0 + ty + 8*j) * outStride + r0 + tx;
    oh[o] = h; ol[o] = f2bf(x - bf2f(h));
  }
}

// ---------------- split-precision GEMM core (bf16 hi/lo, 3 MFMA) ----------------
DEVI void core_split(const u16* __restrict__ Ah, const u16* __restrict__ Al,
                     const u16* __restrict__ Bh, const u16* __restrict__ Bl,
                     int lda, int ldb, int K,
                     u16* Ash, u16* Asl, u16* Bsh, u16* Bsl,
                     f32x4 (&acc)[4][4]){
  const int t = threadIdx.x;
  const int lane = t & 63, w = t >> 6;
  const int l15 = lane & 15, l4 = lane >> 4;
  const int wr = (w >> 1) * 64, wc = (w & 1) * 64;
  for(int kt = 0; kt < K; kt += 32){
    __syncthreads();
    #pragma unroll
    for(int i = 0; i < 2; i++){
      int row = i*64 + (t >> 2);
      int ce  = (t & 3) * 8;
      size_t ao = (size_t)row * lda + kt + ce;
      size_t bo = (size_t)row * ldb + kt + ce;
      gload16(Ah + ao, (char*)Ash + i*4096 + t*16);
      gload16(Al + ao, (char*)Asl + i*4096 + t*16);
      gload16(Bh + bo, (char*)Bsh + i*4096 + t*16);
      gload16(Bl + bo, (char*)Bsl + i*4096 + t*16);
    }
    __syncthreads();
    bf16x8 ah[4], al[4], bh[4], bl[4];
    #pragma unroll
    for(int mi = 0; mi < 4; mi++){
      ah[mi] = *(const bf16x8*)((const char*)Ash + (wr + mi*16 + l15)*64 + l4*16);
      al[mi] = *(const bf16x8*)((const char*)Asl + (wr + mi*16 + l15)*64 + l4*16);
    }
    #pragma unroll
    for(int ni = 0; ni < 4; ni++){
      bh[ni] = *(const bf16x8*)((const char*)Bsh + (wc + ni*16 + l15)*64 + l4*16);
      bl[ni] = *(const bf16x8*)((const char*)Bsl + (wc + ni*16 + l15)*64 + l4*16);
    }
    #pragma unroll
    for(int mi = 0; mi < 4; mi++)
      #pragma unroll
      for(int ni = 0; ni < 4; ni++){
        acc[mi][ni] = __builtin_amdgcn_mfma_f32_16x16x32_bf16(ah[mi], bh[ni], acc[mi][ni], 0, 0, 0);
        acc[mi][ni] = __builtin_amdgcn_mfma_f32_16x16x32_bf16(ah[mi], bl[ni], acc[mi][ni], 0, 0, 0);
        acc[mi][ni] = __builtin_amdgcn_mfma_f32_16x16x32_bf16(al[mi], bh[ni], acc[mi][ni], 0, 0, 0);
      }
  }
}

// ---------------- QK projection, split precision, single f16 output [M][1024] ----------------
__global__ __launch_bounds__(256) void k_qk_split(const u16* __restrict__ Xh, const u16* __restrict__ Xl,
                                                  const u16* __restrict__ Wh, const u16* __restrict__ Wl,
                                                  u16* __restrict__ QK){
  __shared__ u16 Ash[4096], Asl[4096], Bsh[4096], Bsl[4096];
  const int bm = blockIdx.x * 128, bn = blockIdx.y * 128;
  f32x4 acc[4][4] = {};
  core_split(Xh + (size_t)bm*512, Xl + (size_t)bm*512,
             Wh + (size_t)bn*512, Wl + (size_t)bn*512,
             512, 512, 512, Ash, Asl, Bsh, Bsl, acc);
  const int t = threadIdx.x, lane = t & 63, w = t >> 6;
  const int l15 = lane & 15, l4 = lane >> 4;
  const int wr = (w >> 1) * 64, wc = (w & 1) * 64;
  #pragma unroll
  for(int mi = 0; mi < 4; mi++)
    #pragma unroll
    for(int ni = 0; ni < 4; ni++){
      int col = bn + wc + ni*16 + l15;
      #pragma unroll
      for(int r = 0; r < 4; r++){
        int row = bm + wr + mi*16 + l4*4 + r;
        QK[(size_t)row * 1024 + col] = f2h(acc[mi][ni][r]);
      }
    }
}

// ---------------- f16 GEMM core (single MFMA) ----------------
DEVI void core_f16(const u16* __restrict__ A, const u16* __restrict__ B,
                   int lda, int ldb, int K, u16* As, u16* Bs, f32x4 (&acc)[4][4]){
  const int t = threadIdx.x;
  const int lane = t & 63, w = t >> 6;
  const int l15 = lane & 15, l4 = lane >> 4;
  const int wr = (w >> 1) * 64, wc = (w & 1) * 64;
  for(int kt = 0; kt < K; kt += 32){
    __syncthreads();
    #pragma unroll
    for(int i = 0; i < 2; i++){
      int row = i*64 + (t >> 2);
      int ce  = (t & 3) * 8;
      gload16(A + (size_t)row * lda + kt + ce, (char*)As + i*4096 + t*16);
      gload16(B + (size_t)row * ldb + kt + ce, (char*)Bs + i*4096 + t*16);
    }
    __syncthreads();
    f16x8 af[4], bfr[4];
    #pragma unroll
    for(int mi = 0; mi < 4; mi++)
      af[mi] = *(const f16x8*)((const char*)As + (wr + mi*16 + l15)*64 + l4*16);
    #pragma unroll
    for(int ni = 0; ni < 4; ni++)
      bfr[ni] = *(const f16x8*)((const char*)Bs + (wc + ni*16 + l15)*64 + l4*16);
    #pragma unroll
    for(int mi = 0; mi < 4; mi++)
      #pragma unroll
      for(int ni = 0; ni < 4; ni++)
        acc[mi][ni] = __builtin_amdgcn_mfma_f32_16x16x32_f16(af[mi], bfr[ni], acc[mi][ni], 0, 0, 0);
  }
}

// ---------------- causal score GEMM: grid (32,32,nb); z = sub-batch ----------------
__global__ __launch_bounds__(256) void k_score(const u16* __restrict__ QK, int b0,
                                               float* __restrict__ Sp){
  const int kt = blockIdx.x, qt = blockIdx.y;
  if(kt > qt) return;
  const int zb = blockIdx.z;
  const u16* QKb = QK + (size_t)(b0 + zb) * Tt * 1024;
  float* Spz = Sp + (size_t)zb * TRI;
  __shared__ u16 As[4096], Bs[4096];
  const u16* A = QKb + (size_t)(qt*128) * 1024;        // q rows
  const u16* B = QKb + (size_t)(kt*128) * 1024 + 512;  // k rows
  f32x4 acc[4][4] = {};
  core_f16(A, B, 1024, 1024, 512, As, Bs, acc);
  const int t = threadIdx.x, lane = t & 63, w = t >> 6;
  const int l15 = lane & 15, l4 = lane >> 4;
  const int wr = (w >> 1) * 64, wc = (w & 1) * 64;
  const int ldc = (qt + 1) * 128;
  float* C = Spz + PANE(qt) + (size_t)kt*128;
  const bool diag = (kt == qt);
  #pragma unroll
  for(int mi = 0; mi < 4; mi++)
    #pragma unroll
    for(int ni = 0; ni < 4; ni++){
      int cl = wc + ni*16 + l15;
      #pragma unroll
      for(int r = 0; r < 4; r++){
        int rl = wr + mi*16 + l4*4 + r;
        float v = acc[mi][ni][r];
        if(diag && cl > rl) v = -__builtin_inff();
        C[(size_t)rl * ldc + cl] = v;
      }
    }
}

// ---------------- softmax: wave per row; grid (1024,1,nb) ----------------
__global__ __launch_bounds__(256) void k_softmax(float* __restrict__ Sp){
  float* Spz = Sp + (size_t)blockIdx.z * TRI;
  const int w = threadIdx.x >> 6, lane = threadIdx.x & 63;
  const int r = blockIdx.x * 4 + w;           // 0..4095
  const int qt = r >> 7;
  const int L = (qt + 1) * 128, nc = qt + 1;  // chunks of 128 f32 (float2/lane)
  const size_t base = PANE(qt) + (size_t)(r & 127) * L;
  const float2* rp = (const float2*)(Spz + base);
  float2 v[32];
  float mx = -__builtin_inff();
  #pragma unroll
  for(int c = 0; c < 32; c++) if(c < nc){
    v[c] = rp[c*64 + lane];
    mx = fmaxf(mx, fmaxf(v[c].x, v[c].y));
  }
  #pragma unroll
  for(int s = 1; s < 64; s <<= 1) mx = fmaxf(mx, __shfl_xor(mx, s));
  float sm = 0.f;
  #pragma unroll
  for(int c = 0; c < 32; c++) if(c < nc){
    v[c].x = __expf(v[c].x - mx);
    v[c].y = __expf(v[c].y - mx);
    sm += v[c].x + v[c].y;
  }
  #pragma unroll
  for(int s = 1; s < 64; s <<= 1) sm += __shfl_xor(sm, s);
  const float inv = 1.f / sm;
  // bf16 P packed at the START of this row's own f32 region (no cross-row overlap)
  ushort2* wp = (ushort2*)((u16*)Spz + 2*base);
  #pragma unroll
  for(int c = 0; c < 32; c++) if(c < nc){
    ushort2 o; o.x = f2bf(v[c].x * inv); o.y = f2bf(v[c].y * inv);
    wp[c*64 + lane] = o;
  }
}

// ---------------- plain bf16 GEMM core (BN=128) ----------------
DEVI void core_plain(const u16* __restrict__ A, const u16* __restrict__ B,
                     int lda, int ldb, int K, u16* As, u16* Bs, f32x4 (&acc)[4][4]){
  const int t = threadIdx.x;
  const int lane = t & 63, w = t >> 6;
  const int l15 = lane & 15, l4 = lane >> 4;
  const int wr = (w >> 1) * 64, wc = (w & 1) * 64;
  for(int kt = 0; kt < K; kt += 32){
    __syncthreads();
    #pragma unroll
    for(int i = 0; i < 2; i++){
      int row = i*64 + (t >> 2);
      int ce  = (t & 3) * 8;
      gload16(A + (size_t)row * lda + kt + ce, (char*)As + i*4096 + t*16);
      gload16(B + (size_t)row * ldb + kt + ce, (char*)Bs + i*4096 + t*16);
    }
    __syncthreads();
    bf16x8 af[4], bfr[4];
    #pragma unroll
    for(int mi = 0; mi < 4; mi++)
      af[mi] = *(const bf16x8*)((const char*)As + (wr + mi*16 + l15)*64 + l4*16);
    #pragma unroll
    for(int ni = 0; ni < 4; ni++)
      bfr[ni] = *(const bf16x8*)((const char*)Bs + (wc + ni*16 + l15)*64 + l4*16);
    #pragma unroll
    for(int mi = 0; mi < 4; mi++)
      #pragma unroll
      for(int ni = 0; ni < 4; ni++)
        acc[mi][ni] = __builtin_amdgcn_mfma_f32_16x16x32_bf16(af[mi], bfr[ni], acc[mi][ni], 0, 0, 0);
  }
}

// ---------------- plain bf16 GEMM core, BN=64 (more blocks -> better latency hiding) ----------------
DEVI void core_plain64(const u16* __restrict__ A, const u16* __restrict__ B,
                       int lda, int ldb, int K, u16* As, u16* Bs, f32x4 (&acc)[4][2]){
  const int t = threadIdx.x;
  const int lane = t & 63, w = t >> 6;
  const int l15 = lane & 15, l4 = lane >> 4;
  const int wr = (w >> 1) * 64, wc = (w & 1) * 32;
  for(int kt = 0; kt < K; kt += 32){
    __syncthreads();
    #pragma unroll
    for(int i = 0; i < 2; i++){
      int row = i*64 + (t >> 2);
      int ce  = (t & 3) * 8;
      gload16(A + (size_t)row * lda + kt + ce, (char*)As + i*4096 + t*16);
    }
    {
      int row = t >> 2;
      int ce  = (t & 3) * 8;
      gload16(B + (size_t)row * ldb + kt + ce, (char*)Bs + t*16);
    }
    __syncthreads();
    bf16x8 af[4], bfr[2];
    #pragma unroll
    for(int mi = 0; mi < 4; mi++)
      af[mi] = *(const bf16x8*)((const char*)As + (wr + mi*16 + l15)*64 + l4*16);
    #pragma unroll
    for(int ni = 0; ni < 2; ni++)
      bfr[ni] = *(const bf16x8*)((const char*)Bs + (wc + ni*16 + l15)*64 + l4*16);
    #pragma unroll
    for(int mi = 0; mi < 4; mi++)
      #pragma unroll
      for(int ni = 0; ni < 2; ni++)
        acc[mi][ni] = __builtin_amdgcn_mfma_f32_16x16x32_bf16(af[mi], bfr[ni], acc[mi][ni], 0, 0, 0);
  }
}

// ---------------- PV split-K GEMM: grid (4,32,4*nb); atomicAdd f32 ----------------
__global__ __launch_bounds__(256) void k_pv(const u16* __restrict__ Pp, const u16* __restrict__ Vt,
                                            float* __restrict__ NVacc, int b0){
  const int nc = blockIdx.x, qt = blockIdx.y;
  const int kc = blockIdx.z & 3, zb = blockIdx.z >> 2;
  const int L = (qt + 1) * 128;
  const int k0 = kc * 1024;
  if(k0 >= L) return;
  const int kLen = (L - k0) < 1024 ? (L - k0) : 1024;
  __shared__ u16 As[4096], Bs[4096];
  const u16* Ppz = Pp + (size_t)zb * 2 * TRI;
  const u16* Vtb = Vt + (size_t)(b0 + zb) * Cch * Tt;
  float* NVb = NVacc + (size_t)(b0 + zb) * Tt * Cch;
  const u16* A = Ppz + 2*PANE(qt) + k0;                // P rows: u16 stride 2L, data in low L
  const u16* B = Vtb + (size_t)(nc*128) * Tt + k0;     // Vt rows = V columns
  f32x4 acc[4][4] = {};
  core_plain(A, B, 2*L, Tt, kLen, As, Bs, acc);
  const int t = threadIdx.x, lane = t & 63, w = t >> 6;
  const int l15 = lane & 15, l4 = lane >> 4;
  const int wr = (w >> 1) * 64, wc = (w & 1) * 64;
  float* Cb = NVb + (size_t)(qt*128) * Cch + nc*128;
  #pragma unroll
  for(int mi = 0; mi < 4; mi++)
    #pragma unroll
    for(int ni = 0; ni < 4; ni++){
      int cl = wc + ni*16 + l15;
      #pragma unroll
      for(int r = 0; r < 4; r++){
        int rl = wr + mi*16 + l4*4 + r;
        atomicAdd(&Cb[(size_t)rl * Cch + cl], acc[mi][ni][r]);
      }
    }
}

// ---------------- V projection GEMM (BN=64), writes transposed Vt ----------------
__global__ __launch_bounds__(256) void k_vproj(const u16* __restrict__ A,
                                               const u16* __restrict__ Bt,
                                               u16* __restrict__ Vt){
  __shared__ u16 As[4096], Bs[2048];
  const int bm = blockIdx.x * 128, bn = blockIdx.y * 64;
  f32x4 acc[4][2] = {};
  core_plain64(A + (size_t)bm*512, Bt + (size_t)bn*512, 512, 512, 512, As, Bs, acc);
  const int t = threadIdx.x, lane = t & 63, w = t >> 6;
  const int l15 = lane & 15, l4 = lane >> 4;
  const int wr = (w >> 1) * 64, wc = (w & 1) * 32;
  #pragma unroll
  for(int mi = 0; mi < 4; mi++)
    #pragma unroll
    for(int ni = 0; ni < 2; ni++){
      int col = bn + wc + ni*16 + l15;
      #pragma unroll
      for(int r = 0; r < 4; r++){
        int row = bm + wr + mi*16 + l4*4 + r;
        int b = row >> 12, tq = row & 4095;
        Vt[((size_t)b * Cch + col) * Tt + tq] = f2bf(acc[mi][ni][r]);
      }
    }
}

// ---------------- FFN1: +bias, relu, bf16 out (BN=128) ----------------
__global__ __launch_bounds__(256) void k_ffn1(const u16* __restrict__ A,
                                              const u16* __restrict__ Bt,
                                              u16* __restrict__ Hout,
                                              const float* __restrict__ bias){
  __shared__ u16 As[4096], Bs[4096];
  const int bm = blockIdx.x * 128, bn = blockIdx.y * 128;
  f32x4 acc[4][4] = {};
  core_plain(A + (size_t)bm*512, Bt + (size_t)bn*512, 512, 512, 512, As, Bs, acc);
  const int t = threadIdx.x, lane = t & 63, w = t >> 6;
  const int l15 = lane & 15, l4 = lane >> 4;
  const int wr = (w >> 1) * 64, wc = (w & 1) * 64;
  #pragma unroll
  for(int mi = 0; mi < 4; mi++)
    #pragma unroll
    for(int ni = 0; ni < 4; ni++){
      int col = bn + wc + ni*16 + l15;
      float bv = bias[col];
      #pragma unroll
      for(int r = 0; r < 4; r++){
        int row = bm + wr + mi*16 + l4*4 + r;
        float v = acc[mi][ni][r] + bv;
        v = v > 0.f ? v : 0.f;
        Hout[(size_t)row * DFFd + col] = f2bf(v);
      }
    }
}

// ---------------- FFN2 (BN=64): +bias, f32 direct store ----------------
__global__ __launch_bounds__(256) void k_ffn2(const u16* __restrict__ A,
                                              const u16* __restrict__ Bt,
                                              float* __restrict__ out,
                                              const float* __restrict__ bias){
  __shared__ u16 As[4096], Bs[2048];
  const int bm = blockIdx.x * 128, bn = blockIdx.y * 64;
  f32x4 acc[4][2] = {};
  core_plain64(A + (size_t)bm*2048, Bt + (size_t)bn*2048, 2048, 2048, 2048, As, Bs, acc);
  const int t = threadIdx.x, lane = t & 63, w = t >> 6;
  const int l15 = lane & 15, l4 = lane >> 4;
  const int wr = (w >> 1) * 64, wc = (w & 1) * 32;
  #pragma unroll
  for(int mi = 0; mi < 4; mi++)
    #pragma unroll
    for(int ni = 0; ni < 2; ni++){
      int col = bn + wc + ni*16 + l15;
      float bv = bias[col];
      #pragma unroll
      for(int r = 0; r < 4; r++){
        int row = bm + wr + mi*16 + l4*4 + r;
        out[(size_t)row * Cch + col] = acc[mi][ni][r] + bv;
      }
    }
}

// ---------------- small utility kernels ----------------
__global__ void k_zero4(float* __restrict__ p, int n){
  int i = (blockIdx.x * blockDim.x + threadIdx.x) * 4;
  if(i < n) *(f32x4*)(p + i) = (f32x4){0.f,0.f,0.f,0.f};
}
__global__ void k_nv_final(const float* __restrict__ acc, u16* __restrict__ nv, int n){
  int i = (blockIdx.x * blockDim.x + threadIdx.x) * 4;
  if(i < n){
    f32x4 v = *(const f32x4*)(acc + i);
    us4 o; o.x = f2bf(v[0]); o.y = f2bf(v[1]); o.z = f2bf(v[2]); o.w = f2bf(v[3]);
    *(us4*)(nv + i) = o;
  }
}

// ---------------- launch ----------------
extern "C" void kernel_launch(void* const* d_in, const int* in_sizes, int n_in,
                              void* d_out, int out_size, void* d_ws, size_t ws_size,
                              hipStream_t stream){
  (void)in_sizes; (void)n_in; (void)out_size;
  const float* X  = (const float*)d_in[0];
  const float* Wq = (const float*)d_in[1];
  const float* Wk = (const float*)d_in[2];
  const float* Wv = (const float*)d_in[3];
  const float* W1 = (const float*)d_in[4];
  const float* b1 = (const float*)d_in[5];
  const float* W2 = (const float*)d_in[6];
  const float* b2 = (const float*)d_in[7];
  float* out = (float*)d_out;

  // workspace (MiB offsets):
  // [0,16) Xh -> later H(64, spans [0,64)); [16,32) Xl; [32,64) QK f16
  // [64,80) Vt; [80,112) NVacc f32; [112,128) NV bf16; [128,134.5) weights
  // [135, 135+33*nb) S panes (33 MiB each)
  const size_t MB = 1024ull*1024ull;
  char* ws = (char*)d_ws;
  u16*    Xh     = (u16*)(ws + 0);
  u16*    H      = (u16*)(ws + 0);
  u16*    Xl     = (u16*)(ws + 16*MB);
  u16*    QK     = (u16*)(ws + 32*MB);
  u16*    Vt     = (u16*)(ws + 64*MB);
  float*  NVacc  = (float*)(ws + 80*MB);
  u16*    NV     = (u16*)(ws + 112*MB);
  u16*    Wqkh   = (u16*)(ws + 128*MB);
  u16*    Wqkl   = (u16*)(ws + 129*MB);
  u16*    Wvt    = (u16*)(ws + 130*MB);
  u16*    W1t    = (u16*)(ws + 131*MB);
  u16*    W2t    = (u16*)(ws + 133*MB);
  float*  Sp     = (float*)(ws + 135*MB);

  // two S panes need 135 MiB + 2*33 MiB = 201 MiB
  const int nb = (ws_size >= 202ull*MB) ? 2 : 1;

  dim3 tb(32, 8);

  // 1. split-cast X
  k_split_cast<<<Mrows*Cch/4/256, 256, 0, stream>>>(X, Xh, Xl, Mrows*Cch);

  // 2. weight transposes (Wq/Wk split, Wv/W1/W2 plain)
  k_transpose_split<<<dim3(16,16), tb, 0, stream>>>(Wq, Wqkh,           Wqkl,           512, 512);
  k_transpose_split<<<dim3(16,16), tb, 0, stream>>>(Wk, Wqkh + 512*512, Wqkl + 512*512, 512, 512);
  k_transpose_f32_bf16<<<dim3(16,16), tb, 0, stream>>>(Wv, Wvt, 512, 512);
  k_transpose_f32_bf16<<<dim3(64,16), tb, 0, stream>>>(W1, W1t, 2048, 512);
  k_transpose_f32_bf16<<<dim3(16,64), tb, 0, stream>>>(W2, W2t, 512, 2048);

  // 3. QK projection (split-bf16 compute, f16 store); V projection -> transposed Vt (BN=64)
  k_qk_split<<<dim3(128, 8), 256, 0, stream>>>(Xh, Xl, Wqkh, Wqkl, QK);
  k_vproj<<<dim3(128, 8), 256, 0, stream>>>(Xh, Wvt, Vt);

  // 4. attention: paired batches (nb) of score -> softmax -> split-K PV
  k_zero4<<<Mrows*Cch/4/256, 256, 0, stream>>>(NVacc, Mrows*Cch);
  for(int b0 = 0; b0 < Bb; b0 += nb){
    k_score<<<dim3(32, 32, nb), 256, 0, stream>>>(QK, b0, Sp);
    k_softmax<<<dim3(1024, 1, nb), 256, 0, stream>>>(Sp);
    k_pv<<<dim3(4, 32, 4*nb), 256, 0, stream>>>((const u16*)Sp, Vt, NVacc, b0);
  }
  k_nv_final<<<Mrows*Cch/4/256, 256, 0, stream>>>(NVacc, NV, Mrows*Cch);

  // 5. FFN (FFN1 BN=128; FFN2 BN=64 direct store)
  k_ffn1<<<dim3(128, 16), 256, 0, stream>>>(NV, W1t, H, b1);
  k_ffn2<<<dim3(128, 8), 256, 0, stream>>>(H, W2t, out, b2);
}

// Round 9
// 433.797 us; speedup vs baseline: 1.5100x; 1.0502x over previous
//
#include <hip/hip_runtime.h>
#include <stdint.h>

typedef __attribute__((ext_vector_type(8))) short bf16x8;
typedef __attribute__((ext_vector_type(8))) _Float16 f16x8;
typedef __attribute__((ext_vector_type(4))) float f32x4;
typedef __attribute__((ext_vector_type(4))) unsigned short us4;
typedef unsigned short u16;

#define DEVI static __device__ __forceinline__

#define Bb 4
#define Tt 4096
#define Cch 512
#define DFFd 2048
#define Mrows (Bb*Tt)
#define TRI 8650752ull   // f32 elements per packed causal pane = PANE(32)

DEVI u16 f2bf(float f){
  union{float f;unsigned u;} v; v.f = f;
  unsigned r = v.u + 0x7FFFu + ((v.u >> 16) & 1u);
  return (u16)(r >> 16);
}
DEVI float bf2f(u16 h){
  union{unsigned u;float f;} v; v.u = (unsigned)h << 16; return v.f;
}
DEVI u16 f2h(float f){
  union{_Float16 h; u16 u;} v; v.h = (_Float16)f; return v.u;
}
// packed-triangular pane offset (f32 elements): sum_{j<q}(j+1)*128*128
DEVI size_t PANE(int q){ return (size_t)8192 * (size_t)(q*(q+1)); }

DEVI void gload16(const void* g, void* l){
  __builtin_amdgcn_global_load_lds((const __attribute__((address_space(1))) unsigned int*)g,
                                   (__attribute__((address_space(3))) unsigned int*)l, 16, 0, 0);
}

// ---------------- split cast f32 -> (hi, lo) bf16 ----------------
__global__ void k_split_cast(const float* __restrict__ in, u16* __restrict__ hi,
                             u16* __restrict__ lo, int n){
  int i = (blockIdx.x * blockDim.x + threadIdx.x) * 4;
  if(i < n){
    float4 f = *(const float4*)(in + i);
    us4 h, l;
    h.x = f2bf(f.x); l.x = f2bf(f.x - bf2f(h.x));
    h.y = f2bf(f.y); l.y = f2bf(f.y - bf2f(h.y));
    h.z = f2bf(f.z); l.z = f2bf(f.z - bf2f(h.z));
    h.w = f2bf(f.w); l.w = f2bf(f.w - bf2f(h.w));
    *(us4*)(hi + i) = h; *(us4*)(lo + i) = l;
  }
}

// ------------- transpose-cast f32 -> bf16 (plain) -------------
__global__ void k_transpose_f32_bf16(const float* __restrict__ in, u16* __restrict__ out,
                                     int inStride, int outStride){
  __shared__ float tile[32][33];
  int c0 = blockIdx.x * 32, r0 = blockIdx.y * 32;
  int tx = threadIdx.x, ty = threadIdx.y; // (32,8)
  #pragma unroll
  for(int j = 0; j < 4; j++)
    tile[ty + 8*j][tx] = in[(size_t)(r0 + ty + 8*j) * inStride + c0 + tx];
  __syncthreads();
  #pragma unroll
  for(int j = 0; j < 4; j++)
    out[(size_t)(c0 + ty + 8*j) * outStride + r0 + tx] = f2bf(tile[tx][ty + 8*j]);
}

// ------------- transpose-cast f32 -> (hi,lo) bf16 -------------
__global__ void k_transpose_split(const float* __restrict__ in, u16* __restrict__ oh,
                                  u16* __restrict__ ol, int inStride, int outStride){
  __shared__ float tile[32][33];
  int c0 = blockIdx.x * 32, r0 = blockIdx.y * 32;
  int tx = threadIdx.x, ty = threadIdx.y;
  #pragma unroll
  for(int j = 0; j < 4; j++)
    tile[ty + 8*j][tx] = in[(size_t)(r0 + ty + 8*j) * inStride + c0 + tx];
  __syncthreads();
  #pragma unroll
  for(int j = 0; j < 4; j++){
    float x = tile[tx][ty + 8*j];
    u16 h = f2bf(x);
    size_t o = (size_t)(c0 + ty + 8*j) * outStride + r0 + tx;
    oh[o] = h; ol[o] = f2bf(x - bf2f(h));
  }
}

// ---------------- split-precision GEMM core (bf16 hi/lo, 3 MFMA) ----------------
DEVI void core_split(const u16* __restrict__ Ah, const u16* __restrict__ Al,
                     const u16* __restrict__ Bh, const u16* __restrict__ Bl,
                     int lda, int ldb, int K,
                     u16* Ash, u16* Asl, u16* Bsh, u16* Bsl,
                     f32x4 (&acc)[4][4]){
  const int t = threadIdx.x;
  const int lane = t & 63, w = t >> 6;
  const int l15 = lane & 15, l4 = lane >> 4;
  const int wr = (w >> 1) * 64, wc = (w & 1) * 64;
  for(int kt = 0; kt < K; kt += 32){
    __syncthreads();
    #pragma unroll
    for(int i = 0; i < 2; i++){
      int row = i*64 + (t >> 2);
      int ce  = (t & 3) * 8;
      size_t ao = (size_t)row * lda + kt + ce;
      size_t bo = (size_t)row * ldb + kt + ce;
      gload16(Ah + ao, (char*)Ash + i*4096 + t*16);
      gload16(Al + ao, (char*)Asl + i*4096 + t*16);
      gload16(Bh + bo, (char*)Bsh + i*4096 + t*16);
      gload16(Bl + bo, (char*)Bsl + i*4096 + t*16);
    }
    __syncthreads();
    bf16x8 ah[4], al[4], bh[4], bl[4];
    #pragma unroll
    for(int mi = 0; mi < 4; mi++){
      ah[mi] = *(const bf16x8*)((const char*)Ash + (wr + mi*16 + l15)*64 + l4*16);
      al[mi] = *(const bf16x8*)((const char*)Asl + (wr + mi*16 + l15)*64 + l4*16);
    }
    #pragma unroll
    for(int ni = 0; ni < 4; ni++){
      bh[ni] = *(const bf16x8*)((const char*)Bsh + (wc + ni*16 + l15)*64 + l4*16);
      bl[ni] = *(const bf16x8*)((const char*)Bsl + (wc + ni*16 + l15)*64 + l4*16);
    }
    #pragma unroll
    for(int mi = 0; mi < 4; mi++)
      #pragma unroll
      for(int ni = 0; ni < 4; ni++){
        acc[mi][ni] = __builtin_amdgcn_mfma_f32_16x16x32_bf16(ah[mi], bh[ni], acc[mi][ni], 0, 0, 0);
        acc[mi][ni] = __builtin_amdgcn_mfma_f32_16x16x32_bf16(ah[mi], bl[ni], acc[mi][ni], 0, 0, 0);
        acc[mi][ni] = __builtin_amdgcn_mfma_f32_16x16x32_bf16(al[mi], bh[ni], acc[mi][ni], 0, 0, 0);
      }
  }
}

// ---------------- QK projection, split precision, single f16 output [M][1024] ----------------
__global__ __launch_bounds__(256) void k_qk_split(const u16* __restrict__ Xh, const u16* __restrict__ Xl,
                                                  const u16* __restrict__ Wh, const u16* __restrict__ Wl,
                                                  u16* __restrict__ QK){
  __shared__ u16 Ash[4096], Asl[4096], Bsh[4096], Bsl[4096];
  const int bm = blockIdx.x * 128, bn = blockIdx.y * 128;
  f32x4 acc[4][4] = {};
  core_split(Xh + (size_t)bm*512, Xl + (size_t)bm*512,
             Wh + (size_t)bn*512, Wl + (size_t)bn*512,
             512, 512, 512, Ash, Asl, Bsh, Bsl, acc);
  const int t = threadIdx.x, lane = t & 63, w = t >> 6;
  const int l15 = lane & 15, l4 = lane >> 4;
  const int wr = (w >> 1) * 64, wc = (w & 1) * 64;
  #pragma unroll
  for(int mi = 0; mi < 4; mi++)
    #pragma unroll
    for(int ni = 0; ni < 4; ni++){
      int col = bn + wc + ni*16 + l15;
      #pragma unroll
      for(int r = 0; r < 4; r++){
        int row = bm + wr + mi*16 + l4*4 + r;
        QK[(size_t)row * 1024 + col] = f2h(acc[mi][ni][r]);
      }
    }
}

// ---------------- f16 GEMM core (single MFMA) ----------------
DEVI void core_f16(const u16* __restrict__ A, const u16* __restrict__ B,
                   int lda, int ldb, int K, u16* As, u16* Bs, f32x4 (&acc)[4][4]){
  const int t = threadIdx.x;
  const int lane = t & 63, w = t >> 6;
  const int l15 = lane & 15, l4 = lane >> 4;
  const int wr = (w >> 1) * 64, wc = (w & 1) * 64;
  for(int kt = 0; kt < K; kt += 32){
    __syncthreads();
    #pragma unroll
    for(int i = 0; i < 2; i++){
      int row = i*64 + (t >> 2);
      int ce  = (t & 3) * 8;
      gload16(A + (size_t)row * lda + kt + ce, (char*)As + i*4096 + t*16);
      gload16(B + (size_t)row * ldb + kt + ce, (char*)Bs + i*4096 + t*16);
    }
    __syncthreads();
    f16x8 af[4], bfr[4];
    #pragma unroll
    for(int mi = 0; mi < 4; mi++)
      af[mi] = *(const f16x8*)((const char*)As + (wr + mi*16 + l15)*64 + l4*16);
    #pragma unroll
    for(int ni = 0; ni < 4; ni++)
      bfr[ni] = *(const f16x8*)((const char*)Bs + (wc + ni*16 + l15)*64 + l4*16);
    #pragma unroll
    for(int mi = 0; mi < 4; mi++)
      #pragma unroll
      for(int ni = 0; ni < 4; ni++)
        acc[mi][ni] = __builtin_amdgcn_mfma_f32_16x16x32_f16(af[mi], bfr[ni], acc[mi][ni], 0, 0, 0);
  }
}

// ---------------- causal score GEMM: grid (32,32,nb); qt descending (longest-first) ----------------
__global__ __launch_bounds__(256) void k_score(const u16* __restrict__ QK, int b0,
                                               float* __restrict__ Sp){
  const int kt = blockIdx.x, qt = 31 - blockIdx.y;
  if(kt > qt) return;
  const int zb = blockIdx.z;
  const u16* QKb = QK + (size_t)(b0 + zb) * Tt * 1024;
  float* Spz = Sp + (size_t)zb * TRI;
  __shared__ u16 As[4096], Bs[4096];
  const u16* A = QKb + (size_t)(qt*128) * 1024;        // q rows
  const u16* B = QKb + (size_t)(kt*128) * 1024 + 512;  // k rows
  f32x4 acc[4][4] = {};
  core_f16(A, B, 1024, 1024, 512, As, Bs, acc);
  const int t = threadIdx.x, lane = t & 63, w = t >> 6;
  const int l15 = lane & 15, l4 = lane >> 4;
  const int wr = (w >> 1) * 64, wc = (w & 1) * 64;
  const int ldc = (qt + 1) * 128;
  float* C = Spz + PANE(qt) + (size_t)kt*128;
  const bool diag = (kt == qt);
  #pragma unroll
  for(int mi = 0; mi < 4; mi++)
    #pragma unroll
    for(int ni = 0; ni < 4; ni++){
      int cl = wc + ni*16 + l15;
      #pragma unroll
      for(int r = 0; r < 4; r++){
        int rl = wr + mi*16 + l4*4 + r;
        float v = acc[mi][ni][r];
        if(diag && cl > rl) v = -__builtin_inff();
        C[(size_t)rl * ldc + cl] = v;
      }
    }
}

// ---------------- softmax: wave per row; grid (1024,1,nb); longest rows first ----------------
__global__ __launch_bounds__(256) void k_softmax(float* __restrict__ Sp){
  float* Spz = Sp + (size_t)blockIdx.z * TRI;
  const int w = threadIdx.x >> 6, lane = threadIdx.x & 63;
  const int r = (1023 - blockIdx.x) * 4 + w;  // 0..4095, descending qt
  const int qt = r >> 7;
  const int L = (qt + 1) * 128, nc = qt + 1;  // chunks of 128 f32 (float2/lane)
  const size_t base = PANE(qt) + (size_t)(r & 127) * L;
  const float2* rp = (const float2*)(Spz + base);
  float2 v[32];
  float mx = -__builtin_inff();
  #pragma unroll
  for(int c = 0; c < 32; c++) if(c < nc){
    v[c] = rp[c*64 + lane];
    mx = fmaxf(mx, fmaxf(v[c].x, v[c].y));
  }
  #pragma unroll
  for(int s = 1; s < 64; s <<= 1) mx = fmaxf(mx, __shfl_xor(mx, s));
  float sm = 0.f;
  #pragma unroll
  for(int c = 0; c < 32; c++) if(c < nc){
    v[c].x = __expf(v[c].x - mx);
    v[c].y = __expf(v[c].y - mx);
    sm += v[c].x + v[c].y;
  }
  #pragma unroll
  for(int s = 1; s < 64; s <<= 1) sm += __shfl_xor(sm, s);
  const float inv = 1.f / sm;
  // bf16 P packed at the START of this row's own f32 region (no cross-row overlap)
  ushort2* wp = (ushort2*)((u16*)Spz + 2*base);
  #pragma unroll
  for(int c = 0; c < 32; c++) if(c < nc){
    ushort2 o; o.x = f2bf(v[c].x * inv); o.y = f2bf(v[c].y * inv);
    wp[c*64 + lane] = o;
  }
}

// ---------------- plain bf16 GEMM core (BN=128) ----------------
DEVI void core_plain(const u16* __restrict__ A, const u16* __restrict__ B,
                     int lda, int ldb, int K, u16* As, u16* Bs, f32x4 (&acc)[4][4]){
  const int t = threadIdx.x;
  const int lane = t & 63, w = t >> 6;
  const int l15 = lane & 15, l4 = lane >> 4;
  const int wr = (w >> 1) * 64, wc = (w & 1) * 64;
  for(int kt = 0; kt < K; kt += 32){
    __syncthreads();
    #pragma unroll
    for(int i = 0; i < 2; i++){
      int row = i*64 + (t >> 2);
      int ce  = (t & 3) * 8;
      gload16(A + (size_t)row * lda + kt + ce, (char*)As + i*4096 + t*16);
      gload16(B + (size_t)row * ldb + kt + ce, (char*)Bs + i*4096 + t*16);
    }
    __syncthreads();
    bf16x8 af[4], bfr[4];
    #pragma unroll
    for(int mi = 0; mi < 4; mi++)
      af[mi] = *(const bf16x8*)((const char*)As + (wr + mi*16 + l15)*64 + l4*16);
    #pragma unroll
    for(int ni = 0; ni < 4; ni++)
      bfr[ni] = *(const bf16x8*)((const char*)Bs + (wc + ni*16 + l15)*64 + l4*16);
    #pragma unroll
    for(int mi = 0; mi < 4; mi++)
      #pragma unroll
      for(int ni = 0; ni < 4; ni++)
        acc[mi][ni] = __builtin_amdgcn_mfma_f32_16x16x32_bf16(af[mi], bfr[ni], acc[mi][ni], 0, 0, 0);
  }
}

// ---------------- plain bf16 GEMM core, BN=64 ----------------
DEVI void core_plain64(const u16* __restrict__ A, const u16* __restrict__ B,
                       int lda, int ldb, int K, u16* As, u16* Bs, f32x4 (&acc)[4][2]){
  const int t = threadIdx.x;
  const int lane = t & 63, w = t >> 6;
  const int l15 = lane & 15, l4 = lane >> 4;
  const int wr = (w >> 1) * 64, wc = (w & 1) * 32;
  for(int kt = 0; kt < K; kt += 32){
    __syncthreads();
    #pragma unroll
    for(int i = 0; i < 2; i++){
      int row = i*64 + (t >> 2);
      int ce  = (t & 3) * 8;
      gload16(A + (size_t)row * lda + kt + ce, (char*)As + i*4096 + t*16);
    }
    {
      int row = t >> 2;
      int ce  = (t & 3) * 8;
      gload16(B + (size_t)row * ldb + kt + ce, (char*)Bs + t*16);
    }
    __syncthreads();
    bf16x8 af[4], bfr[2];
    #pragma unroll
    for(int mi = 0; mi < 4; mi++)
      af[mi] = *(const bf16x8*)((const char*)As + (wr + mi*16 + l15)*64 + l4*16);
    #pragma unroll
    for(int ni = 0; ni < 2; ni++)
      bfr[ni] = *(const bf16x8*)((const char*)Bs + (wc + ni*16 + l15)*64 + l4*16);
    #pragma unroll
    for(int mi = 0; mi < 4; mi++)
      #pragma unroll
      for(int ni = 0; ni < 2; ni++)
        acc[mi][ni] = __builtin_amdgcn_mfma_f32_16x16x32_bf16(af[mi], bfr[ni], acc[mi][ni], 0, 0, 0);
  }
}

// ---------------- PV split-K GEMM: grid (4,32,4*nb); qt descending; atomicAdd f32 ----------------
__global__ __launch_bounds__(256) void k_pv(const u16* __restrict__ Pp, const u16* __restrict__ Vt,
                                            float* __restrict__ NVacc, int b0){
  const int nc = blockIdx.x, qt = 31 - blockIdx.y;
  const int kc = blockIdx.z & 3, zb = blockIdx.z >> 2;
  const int L = (qt + 1) * 128;
  const int k0 = kc * 1024;
  if(k0 >= L) return;
  const int kLen = (L - k0) < 1024 ? (L - k0) : 1024;
  __shared__ u16 As[4096], Bs[4096];
  const u16* Ppz = Pp + (size_t)zb * 2 * TRI;
  const u16* Vtb = Vt + (size_t)(b0 + zb) * Cch * Tt;
  float* NVb = NVacc + (size_t)(b0 + zb) * Tt * Cch;
  const u16* A = Ppz + 2*PANE(qt) + k0;                // P rows: u16 stride 2L, data in low L
  const u16* B = Vtb + (size_t)(nc*128) * Tt + k0;     // Vt rows = V columns
  f32x4 acc[4][4] = {};
  core_plain(A, B, 2*L, Tt, kLen, As, Bs, acc);
  const int t = threadIdx.x, lane = t & 63, w = t >> 6;
  const int l15 = lane & 15, l4 = lane >> 4;
  const int wr = (w >> 1) * 64, wc = (w & 1) * 64;
  float* Cb = NVb + (size_t)(qt*128) * Cch + nc*128;
  #pragma unroll
  for(int mi = 0; mi < 4; mi++)
    #pragma unroll
    for(int ni = 0; ni < 4; ni++){
      int cl = wc + ni*16 + l15;
      #pragma unroll
      for(int r = 0; r < 4; r++){
        int rl = wr + mi*16 + l4*4 + r;
        atomicAdd(&Cb[(size_t)rl * Cch + cl], acc[mi][ni][r]);
      }
    }
}

// ---------------- V projection GEMM (BN=64), writes transposed Vt ----------------
__global__ __launch_bounds__(256) void k_vproj(const u16* __restrict__ A,
                                               const u16* __restrict__ Bt,
                                               u16* __restrict__ Vt){
  __shared__ u16 As[4096], Bs[2048];
  const int bm = blockIdx.x * 128, bn = blockIdx.y * 64;
  f32x4 acc[4][2] = {};
  core_plain64(A + (size_t)bm*512, Bt + (size_t)bn*512, 512, 512, 512, As, Bs, acc);
  const int t = threadIdx.x, lane = t & 63, w = t >> 6;
  const int l15 = lane & 15, l4 = lane >> 4;
  const int wr = (w >> 1) * 64, wc = (w & 1) * 32;
  #pragma unroll
  for(int mi = 0; mi < 4; mi++)
    #pragma unroll
    for(int ni = 0; ni < 2; ni++){
      int col = bn + wc + ni*16 + l15;
      #pragma unroll
      for(int r = 0; r < 4; r++){
        int row = bm + wr + mi*16 + l4*4 + r;
        int b = row >> 12, tq = row & 4095;
        Vt[((size_t)b * Cch + col) * Tt + tq] = f2bf(acc[mi][ni][r]);
      }
    }
}

// ---------------- FFN1: +bias, relu, bf16 out (BN=128) ----------------
__global__ __launch_bounds__(256) void k_ffn1(const u16* __restrict__ A,
                                              const u16* __restrict__ Bt,
                                              u16* __restrict__ Hout,
                                              const float* __restrict__ bias){
  __shared__ u16 As[4096], Bs[4096];
  const int bm = blockIdx.x * 128, bn = blockIdx.y * 128;
  f32x4 acc[4][4] = {};
  core_plain(A + (size_t)bm*512, Bt + (size_t)bn*512, 512, 512, 512, As, Bs, acc);
  const int t = threadIdx.x, lane = t & 63, w = t >> 6;
  const int l15 = lane & 15, l4 = lane >> 4;
  const int wr = (w >> 1) * 64, wc = (w & 1) * 64;
  #pragma unroll
  for(int mi = 0; mi < 4; mi++)
    #pragma unroll
    for(int ni = 0; ni < 4; ni++){
      int col = bn + wc + ni*16 + l15;
      float bv = bias[col];
      #pragma unroll
      for(int r = 0; r < 4; r++){
        int row = bm + wr + mi*16 + l4*4 + r;
        float v = acc[mi][ni][r] + bv;
        v = v > 0.f ? v : 0.f;
        Hout[(size_t)row * DFFd + col] = f2bf(v);
      }
    }
}

// ---------------- FFN2 (BN=64): +bias, f32 direct store ----------------
__global__ __launch_bounds__(256) void k_ffn2(const u16* __restrict__ A,
                                              const u16* __restrict__ Bt,
                                              float* __restrict__ out,
                                              const float* __restrict__ bias){
  __shared__ u16 As[4096], Bs[2048];
  const int bm = blockIdx.x * 128, bn = blockIdx.y * 64;
  f32x4 acc[4][2] = {};
  core_plain64(A + (size_t)bm*2048, Bt + (size_t)bn*2048, 2048, 2048, 2048, As, Bs, acc);
  const int t = threadIdx.x, lane = t & 63, w = t >> 6;
  const int l15 = lane & 15, l4 = lane >> 4;
  const int wr = (w >> 1) * 64, wc = (w & 1) * 32;
  #pragma unroll
  for(int mi = 0; mi < 4; mi++)
    #pragma unroll
    for(int ni = 0; ni < 2; ni++){
      int col = bn + wc + ni*16 + l15;
      float bv = bias[col];
      #pragma unroll
      for(int r = 0; r < 4; r++){
        int row = bm + wr + mi*16 + l4*4 + r;
        out[(size_t)row * Cch + col] = acc[mi][ni][r] + bv;
      }
    }
}

// ---------------- small utility kernels ----------------
__global__ void k_zero4(float* __restrict__ p, int n){
  int i = (blockIdx.x * blockDim.x + threadIdx.x) * 4;
  if(i < n) *(f32x4*)(p + i) = (f32x4){0.f,0.f,0.f,0.f};
}
__global__ void k_nv_final(const float* __restrict__ acc, u16* __restrict__ nv, int n){
  int i = (blockIdx.x * blockDim.x + threadIdx.x) * 4;
  if(i < n){
    f32x4 v = *(const f32x4*)(acc + i);
    us4 o; o.x = f2bf(v[0]); o.y = f2bf(v[1]); o.z = f2bf(v[2]); o.w = f2bf(v[3]);
    *(us4*)(nv + i) = o;
  }
}

// ---------------- launch ----------------
extern "C" void kernel_launch(void* const* d_in, const int* in_sizes, int n_in,
                              void* d_out, int out_size, void* d_ws, size_t ws_size,
                              hipStream_t stream){
  (void)in_sizes; (void)n_in; (void)out_size;
  const float* X  = (const float*)d_in[0];
  const float* Wq = (const float*)d_in[1];
  const float* Wk = (const float*)d_in[2];
  const float* Wv = (const float*)d_in[3];
  const float* W1 = (const float*)d_in[4];
  const float* b1 = (const float*)d_in[5];
  const float* W2 = (const float*)d_in[6];
  const float* b2 = (const float*)d_in[7];
  float* out = (float*)d_out;

  // Parametric workspace layout:
  //   [0, nb*PANE_B)  : S panes (overlaps Xh[0,16M)+Xl[16M,32M) at proj time; H[0,64M) at FFN time)
  //   then QK(32M) | Vt(16M) | NVacc(32M) | NV(16M) | weights(6.5M)
  // Peak = nb*33MiB + 102.5MiB  ->  nb=4:234.5  nb=2:168.5  nb=1:135.5
  const size_t MB = 1024ull*1024ull;
  const size_t PANE_B = (size_t)TRI * 4;   // 34,603,008 B = 33 MiB
  char* ws = (char*)d_ws;

  int nb = 1;
  if(ws_size >= 4*PANE_B + 103*MB) nb = 4;
  else if(ws_size >= 2*PANE_B + 103*MB) nb = 2;

  float* Sp = (float*)ws;
  u16*   Xh = (u16*)ws;
  u16*   Xl = (u16*)(ws + 16*MB);
  u16*   H  = (u16*)ws;
  size_t off = (size_t)nb * PANE_B;
  if(off < 32*MB) off = 32*MB;
  u16*   QK    = (u16*)(ws + off);  off += 32*MB;
  u16*   Vt    = (u16*)(ws + off);  off += 16*MB;
  float* NVacc = (float*)(ws + off); off += 32*MB;
  u16*   NV    = (u16*)(ws + off);  off += 16*MB;
  u16*   Wqkh  = (u16*)(ws + off);  off += 1*MB;
  u16*   Wqkl  = (u16*)(ws + off);  off += 1*MB;
  u16*   Wvt   = (u16*)(ws + off);  off += 1*MB;
  u16*   W1t   = (u16*)(ws + off);  off += 2*MB;
  u16*   W2t   = (u16*)(ws + off);

  dim3 tb(32, 8);

  // 1. split-cast X
  k_split_cast<<<Mrows*Cch/4/256, 256, 0, stream>>>(X, Xh, Xl, Mrows*Cch);

  // 2. weight transposes (Wq/Wk split, Wv/W1/W2 plain)
  k_transpose_split<<<dim3(16,16), tb, 0, stream>>>(Wq, Wqkh,           Wqkl,           512, 512);
  k_transpose_split<<<dim3(16,16), tb, 0, stream>>>(Wk, Wqkh + 512*512, Wqkl + 512*512, 512, 512);
  k_transpose_f32_bf16<<<dim3(16,16), tb, 0, stream>>>(Wv, Wvt, 512, 512);
  k_transpose_f32_bf16<<<dim3(64,16), tb, 0, stream>>>(W1, W1t, 2048, 512);
  k_transpose_f32_bf16<<<dim3(16,64), tb, 0, stream>>>(W2, W2t, 512, 2048);

  // 3. QK projection (split-bf16 compute, f16 store); V projection -> transposed Vt (BN=64)
  k_qk_split<<<dim3(128, 8), 256, 0, stream>>>(Xh, Xl, Wqkh, Wqkl, QK);
  k_vproj<<<dim3(128, 8), 256, 0, stream>>>(Xh, Wvt, Vt);

  // 4. attention: nb batches per pass of score -> softmax -> split-K PV (longest-first order)
  k_zero4<<<Mrows*Cch/4/256, 256, 0, stream>>>(NVacc, Mrows*Cch);
  for(int b0 = 0; b0 < Bb; b0 += nb){
    k_score<<<dim3(32, 32, nb), 256, 0, stream>>>(QK, b0, Sp);
    k_softmax<<<dim3(1024, 1, nb), 256, 0, stream>>>(Sp);
    k_pv<<<dim3(4, 32, 4*nb), 256, 0, stream>>>((const u16*)Sp, Vt, NVacc, b0);
  }
  k_nv_final<<<Mrows*Cch/4/256, 256, 0, stream>>>(NVacc, NV, Mrows*Cch);

  // 5. FFN (FFN1 BN=128; FFN2 BN=64 direct store)
  k_ffn1<<<dim3(128, 16), 256, 0, stream>>>(NV, W1t, H, b1);
  k_ffn2<<<dim3(128, 8), 256, 0, stream>>>(H, W2t, out, b2);
}

// Round 10
// 408.550 us; speedup vs baseline: 1.6033x; 1.0618x over previous
//
#include <hip/hip_runtime.h>
#include <stdint.h>

typedef __attribute__((ext_vector_type(8))) short bf16x8;
typedef __attribute__((ext_vector_type(8))) _Float16 f16x8;
typedef __attribute__((ext_vector_type(4))) float f32x4;
typedef __attribute__((ext_vector_type(4))) unsigned short us4;
typedef unsigned short u16;

#define DEVI static __device__ __forceinline__

#define Bb 4
#define Tt 4096
#define Cch 512
#define DFFd 2048
#define Mrows (Bb*Tt)
#define TRI 8650752ull   // u16 elements per packed causal pane = PANE(32)

DEVI u16 f2bf(float f){
  union{float f;unsigned u;} v; v.f = f;
  unsigned r = v.u + 0x7FFFu + ((v.u >> 16) & 1u);
  return (u16)(r >> 16);
}
DEVI float bf2f(u16 h){
  union{unsigned u;float f;} v; v.u = (unsigned)h << 16; return v.f;
}
DEVI u16 f2h(float f){
  union{_Float16 h; u16 u;} v; v.h = (_Float16)f; return v.u;
}
DEVI float h2f(u16 h){
  union{u16 u; _Float16 h;} v; v.u = h; return (float)v.h;
}
// packed-triangular pane offset (u16 elements): sum_{j<q}(j+1)*128*128
DEVI size_t PANE(int q){ return (size_t)8192 * (size_t)(q*(q+1)); }

DEVI void gload16(const void* g, void* l){
  __builtin_amdgcn_global_load_lds((const __attribute__((address_space(1))) unsigned int*)g,
                                   (__attribute__((address_space(3))) unsigned int*)l, 16, 0, 0);
}

// ---------------- split cast f32 -> (hi, lo) bf16 ----------------
__global__ void k_split_cast(const float* __restrict__ in, u16* __restrict__ hi,
                             u16* __restrict__ lo, int n){
  int i = (blockIdx.x * blockDim.x + threadIdx.x) * 4;
  if(i < n){
    float4 f = *(const float4*)(in + i);
    us4 h, l;
    h.x = f2bf(f.x); l.x = f2bf(f.x - bf2f(h.x));
    h.y = f2bf(f.y); l.y = f2bf(f.y - bf2f(h.y));
    h.z = f2bf(f.z); l.z = f2bf(f.z - bf2f(h.z));
    h.w = f2bf(f.w); l.w = f2bf(f.w - bf2f(h.w));
    *(us4*)(hi + i) = h; *(us4*)(lo + i) = l;
  }
}

// ------------- transpose-cast f32 -> bf16 (plain) -------------
__global__ void k_transpose_f32_bf16(const float* __restrict__ in, u16* __restrict__ out,
                                     int inStride, int outStride){
  __shared__ float tile[32][33];
  int c0 = blockIdx.x * 32, r0 = blockIdx.y * 32;
  int tx = threadIdx.x, ty = threadIdx.y; // (32,8)
  #pragma unroll
  for(int j = 0; j < 4; j++)
    tile[ty + 8*j][tx] = in[(size_t)(r0 + ty + 8*j) * inStride + c0 + tx];
  __syncthreads();
  #pragma unroll
  for(int j = 0; j < 4; j++)
    out[(size_t)(c0 + ty + 8*j) * outStride + r0 + tx] = f2bf(tile[tx][ty + 8*j]);
}

// ------------- transpose-cast f32 -> (hi,lo) bf16 -------------
__global__ void k_transpose_split(const float* __restrict__ in, u16* __restrict__ oh,
                                  u16* __restrict__ ol, int inStride, int outStride){
  __shared__ float tile[32][33];
  int c0 = blockIdx.x * 32, r0 = blockIdx.y * 32;
  int tx = threadIdx.x, ty = threadIdx.y;
  #pragma unroll
  for(int j = 0; j < 4; j++)
    tile[ty + 8*j][tx] = in[(size_t)(r0 + ty + 8*j) * inStride + c0 + tx];
  __syncthreads();
  #pragma unroll
  for(int j = 0; j < 4; j++){
    float x = tile[tx][ty + 8*j];
    u16 h = f2bf(x);
    size_t o = (size_t)(c0 + ty + 8*j) * outStride + r0 + tx;
    oh[o] = h; ol[o] = f2bf(x - bf2f(h));
  }
}

// ---------------- split-precision GEMM core (bf16 hi/lo, 3 MFMA) ----------------
DEVI void core_split(const u16* __restrict__ Ah, const u16* __restrict__ Al,
                     const u16* __restrict__ Bh, const u16* __restrict__ Bl,
                     int lda, int ldb, int K,
                     u16* Ash, u16* Asl, u16* Bsh, u16* Bsl,
                     f32x4 (&acc)[4][4]){
  const int t = threadIdx.x;
  const int lane = t & 63, w = t >> 6;
  const int l15 = lane & 15, l4 = lane >> 4;
  const int wr = (w >> 1) * 64, wc = (w & 1) * 64;
  for(int kt = 0; kt < K; kt += 32){
    __syncthreads();
    #pragma unroll
    for(int i = 0; i < 2; i++){
      int row = i*64 + (t >> 2);
      int ce  = (t & 3) * 8;
      size_t ao = (size_t)row * lda + kt + ce;
      size_t bo = (size_t)row * ldb + kt + ce;
      gload16(Ah + ao, (char*)Ash + i*4096 + t*16);
      gload16(Al + ao, (char*)Asl + i*4096 + t*16);
      gload16(Bh + bo, (char*)Bsh + i*4096 + t*16);
      gload16(Bl + bo, (char*)Bsl + i*4096 + t*16);
    }
    __syncthreads();
    bf16x8 ah[4], al[4], bh[4], bl[4];
    #pragma unroll
    for(int mi = 0; mi < 4; mi++){
      ah[mi] = *(const bf16x8*)((const char*)Ash + (wr + mi*16 + l15)*64 + l4*16);
      al[mi] = *(const bf16x8*)((const char*)Asl + (wr + mi*16 + l15)*64 + l4*16);
    }
    #pragma unroll
    for(int ni = 0; ni < 4; ni++){
      bh[ni] = *(const bf16x8*)((const char*)Bsh + (wc + ni*16 + l15)*64 + l4*16);
      bl[ni] = *(const bf16x8*)((const char*)Bsl + (wc + ni*16 + l15)*64 + l4*16);
    }
    #pragma unroll
    for(int mi = 0; mi < 4; mi++)
      #pragma unroll
      for(int ni = 0; ni < 4; ni++){
        acc[mi][ni] = __builtin_amdgcn_mfma_f32_16x16x32_bf16(ah[mi], bh[ni], acc[mi][ni], 0, 0, 0);
        acc[mi][ni] = __builtin_amdgcn_mfma_f32_16x16x32_bf16(ah[mi], bl[ni], acc[mi][ni], 0, 0, 0);
        acc[mi][ni] = __builtin_amdgcn_mfma_f32_16x16x32_bf16(al[mi], bh[ni], acc[mi][ni], 0, 0, 0);
      }
  }
}

// ---------------- QK projection, split precision, single f16 output [M][1024] ----------------
__global__ __launch_bounds__(256) void k_qk_split(const u16* __restrict__ Xh, const u16* __restrict__ Xl,
                                                  const u16* __restrict__ Wh, const u16* __restrict__ Wl,
                                                  u16* __restrict__ QK){
  __shared__ u16 Ash[4096], Asl[4096], Bsh[4096], Bsl[4096];
  const int bm = blockIdx.x * 128, bn = blockIdx.y * 128;
  f32x4 acc[4][4] = {};
  core_split(Xh + (size_t)bm*512, Xl + (size_t)bm*512,
             Wh + (size_t)bn*512, Wl + (size_t)bn*512,
             512, 512, 512, Ash, Asl, Bsh, Bsl, acc);
  const int t = threadIdx.x, lane = t & 63, w = t >> 6;
  const int l15 = lane & 15, l4 = lane >> 4;
  const int wr = (w >> 1) * 64, wc = (w & 1) * 64;
  #pragma unroll
  for(int mi = 0; mi < 4; mi++)
    #pragma unroll
    for(int ni = 0; ni < 4; ni++){
      int col = bn + wc + ni*16 + l15;
      #pragma unroll
      for(int r = 0; r < 4; r++){
        int row = bm + wr + mi*16 + l4*4 + r;
        QK[(size_t)row * 1024 + col] = f2h(acc[mi][ni][r]);
      }
    }
}

// ---------------- f16 GEMM core (single MFMA) ----------------
DEVI void core_f16(const u16* __restrict__ A, const u16* __restrict__ B,
                   int lda, int ldb, int K, u16* As, u16* Bs, f32x4 (&acc)[4][4]){
  const int t = threadIdx.x;
  const int lane = t & 63, w = t >> 6;
  const int l15 = lane & 15, l4 = lane >> 4;
  const int wr = (w >> 1) * 64, wc = (w & 1) * 64;
  for(int kt = 0; kt < K; kt += 32){
    __syncthreads();
    #pragma unroll
    for(int i = 0; i < 2; i++){
      int row = i*64 + (t >> 2);
      int ce  = (t & 3) * 8;
      gload16(A + (size_t)row * lda + kt + ce, (char*)As + i*4096 + t*16);
      gload16(B + (size_t)row * ldb + kt + ce, (char*)Bs + i*4096 + t*16);
    }
    __syncthreads();
    f16x8 af[4], bfr[4];
    #pragma unroll
    for(int mi = 0; mi < 4; mi++)
      af[mi] = *(const f16x8*)((const char*)As + (wr + mi*16 + l15)*64 + l4*16);
    #pragma unroll
    for(int ni = 0; ni < 4; ni++)
      bfr[ni] = *(const f16x8*)((const char*)Bs + (wc + ni*16 + l15)*64 + l4*16);
    #pragma unroll
    for(int mi = 0; mi < 4; mi++)
      #pragma unroll
      for(int ni = 0; ni < 4; ni++)
        acc[mi][ni] = __builtin_amdgcn_mfma_f32_16x16x32_f16(af[mi], bfr[ni], acc[mi][ni], 0, 0, 0);
  }
}

// ---------------- causal score GEMM: grid (32,32,nb); qt descending; f16 packed out ----------------
__global__ __launch_bounds__(256) void k_score(const u16* __restrict__ QK, int b0,
                                               u16* __restrict__ Sp){
  const int kt = blockIdx.x, qt = 31 - blockIdx.y;
  if(kt > qt) return;
  const int zb = blockIdx.z;
  const u16* QKb = QK + (size_t)(b0 + zb) * Tt * 1024;
  u16* Spz = Sp + (size_t)zb * TRI;
  __shared__ u16 As[4096], Bs[4096];
  const u16* A = QKb + (size_t)(qt*128) * 1024;        // q rows
  const u16* B = QKb + (size_t)(kt*128) * 1024 + 512;  // k rows
  f32x4 acc[4][4] = {};
  core_f16(A, B, 1024, 1024, 512, As, Bs, acc);
  const int t = threadIdx.x, lane = t & 63, w = t >> 6;
  const int l15 = lane & 15, l4 = lane >> 4;
  const int wr = (w >> 1) * 64, wc = (w & 1) * 64;
  const int ldc = (qt + 1) * 128;
  u16* C = Spz + PANE(qt) + (size_t)kt*128;
  const bool diag = (kt == qt);
  #pragma unroll
  for(int mi = 0; mi < 4; mi++)
    #pragma unroll
    for(int ni = 0; ni < 4; ni++){
      int cl = wc + ni*16 + l15;
      #pragma unroll
      for(int r = 0; r < 4; r++){
        int rl = wr + mi*16 + l4*4 + r;
        float v = acc[mi][ni][r];
        if(diag && cl > rl) v = -__builtin_inff();
        C[(size_t)rl * ldc + cl] = f2h(v);
      }
    }
}

// ---------------- softmax: wave per row; f16 S -> normalized f16 P in place ----------------
__global__ __launch_bounds__(256) void k_softmax(u16* __restrict__ Sp){
  u16* Spz = Sp + (size_t)blockIdx.z * TRI;
  const int w = threadIdx.x >> 6, lane = threadIdx.x & 63;
  const int r = (1023 - blockIdx.x) * 4 + w;  // 0..4095, descending qt
  const int qt = r >> 7;
  const int nc = qt + 1;                      // chunks of 128 u16 (ushort2/lane)
  const int L = nc * 128;
  const size_t base = PANE(qt) + (size_t)(r & 127) * L;
  ushort2* rp = (ushort2*)(Spz + base);
  float2 v[32];
  float mx = -__builtin_inff();
  #pragma unroll
  for(int c = 0; c < 32; c++) if(c < nc){
    ushort2 h = rp[c*64 + lane];
    v[c].x = h2f(h.x); v[c].y = h2f(h.y);
    mx = fmaxf(mx, fmaxf(v[c].x, v[c].y));
  }
  #pragma unroll
  for(int s = 1; s < 64; s <<= 1) mx = fmaxf(mx, __shfl_xor(mx, s));
  float sm = 0.f;
  #pragma unroll
  for(int c = 0; c < 32; c++) if(c < nc){
    v[c].x = __expf(v[c].x - mx);
    v[c].y = __expf(v[c].y - mx);
    sm += v[c].x + v[c].y;
  }
  #pragma unroll
  for(int s = 1; s < 64; s <<= 1) sm += __shfl_xor(sm, s);
  const float inv = 1.f / sm;
  #pragma unroll
  for(int c = 0; c < 32; c++) if(c < nc){
    ushort2 o; o.x = f2h(v[c].x * inv); o.y = f2h(v[c].y * inv);
    rp[c*64 + lane] = o;
  }
}

// ---------------- plain bf16 GEMM core (BN=128) ----------------
DEVI void core_plain(const u16* __restrict__ A, const u16* __restrict__ B,
                     int lda, int ldb, int K, u16* As, u16* Bs, f32x4 (&acc)[4][4]){
  const int t = threadIdx.x;
  const int lane = t & 63, w = t >> 6;
  const int l15 = lane & 15, l4 = lane >> 4;
  const int wr = (w >> 1) * 64, wc = (w & 1) * 64;
  for(int kt = 0; kt < K; kt += 32){
    __syncthreads();
    #pragma unroll
    for(int i = 0; i < 2; i++){
      int row = i*64 + (t >> 2);
      int ce  = (t & 3) * 8;
      gload16(A + (size_t)row * lda + kt + ce, (char*)As + i*4096 + t*16);
      gload16(B + (size_t)row * ldb + kt + ce, (char*)Bs + i*4096 + t*16);
    }
    __syncthreads();
    bf16x8 af[4], bfr[4];
    #pragma unroll
    for(int mi = 0; mi < 4; mi++)
      af[mi] = *(const bf16x8*)((const char*)As + (wr + mi*16 + l15)*64 + l4*16);
    #pragma unroll
    for(int ni = 0; ni < 4; ni++)
      bfr[ni] = *(const bf16x8*)((const char*)Bs + (wc + ni*16 + l15)*64 + l4*16);
    #pragma unroll
    for(int mi = 0; mi < 4; mi++)
      #pragma unroll
      for(int ni = 0; ni < 4; ni++)
        acc[mi][ni] = __builtin_amdgcn_mfma_f32_16x16x32_bf16(af[mi], bfr[ni], acc[mi][ni], 0, 0, 0);
  }
}

// ---------------- plain bf16 GEMM core, BN=64 ----------------
DEVI void core_plain64(const u16* __restrict__ A, const u16* __restrict__ B,
                       int lda, int ldb, int K, u16* As, u16* Bs, f32x4 (&acc)[4][2]){
  const int t = threadIdx.x;
  const int lane = t & 63, w = t >> 6;
  const int l15 = lane & 15, l4 = lane >> 4;
  const int wr = (w >> 1) * 64, wc = (w & 1) * 32;
  for(int kt = 0; kt < K; kt += 32){
    __syncthreads();
    #pragma unroll
    for(int i = 0; i < 2; i++){
      int row = i*64 + (t >> 2);
      int ce  = (t & 3) * 8;
      gload16(A + (size_t)row * lda + kt + ce, (char*)As + i*4096 + t*16);
    }
    {
      int row = t >> 2;
      int ce  = (t & 3) * 8;
      gload16(B + (size_t)row * ldb + kt + ce, (char*)Bs + t*16);
    }
    __syncthreads();
    bf16x8 af[4], bfr[2];
    #pragma unroll
    for(int mi = 0; mi < 4; mi++)
      af[mi] = *(const bf16x8*)((const char*)As + (wr + mi*16 + l15)*64 + l4*16);
    #pragma unroll
    for(int ni = 0; ni < 2; ni++)
      bfr[ni] = *(const bf16x8*)((const char*)Bs + (wc + ni*16 + l15)*64 + l4*16);
    #pragma unroll
    for(int mi = 0; mi < 4; mi++)
      #pragma unroll
      for(int ni = 0; ni < 2; ni++)
        acc[mi][ni] = __builtin_amdgcn_mfma_f32_16x16x32_bf16(af[mi], bfr[ni], acc[mi][ni], 0, 0, 0);
  }
}

// ---------------- PV split-K GEMM (f16): P contiguous, V blocked; atomicAdd f32 ----------------
__global__ __launch_bounds__(256) void k_pv(const u16* __restrict__ Pp, const u16* __restrict__ Vg,
                                            float* __restrict__ NVacc, int b0){
  const int nc = blockIdx.x, qt = 31 - blockIdx.y;
  const int kc = blockIdx.z & 3, zb = blockIdx.z >> 2;
  const int L = (qt + 1) * 128;
  const int k0 = kc * 1024;
  if(k0 >= L) return;
  const int kLen = (L - k0) < 1024 ? (L - k0) : 1024;
  __shared__ u16 As[4096], Bs[4096];
  const u16* A = Pp + (size_t)zb * TRI + PANE(qt) + k0;       // f16 P, row stride L
  const u16* Vgb = Vg + (size_t)(b0 + zb) * Cch * Tt;         // blocked [t/32][c][t%32] f16
  float* NVb = NVacc + (size_t)(b0 + zb) * Tt * Cch;
  const int t = threadIdx.x, lane = t & 63, w = t >> 6;
  const int l15 = lane & 15, l4 = lane >> 4;
  const int wr = (w >> 1) * 64, wc = (w & 1) * 64;
  f32x4 acc[4][4] = {};
  for(int kt = 0; kt < kLen; kt += 32){
    __syncthreads();
    #pragma unroll
    for(int i = 0; i < 2; i++){
      int row = i*64 + (t >> 2);
      int ce  = (t & 3) * 8;
      gload16(A + (size_t)row * L + kt + ce, (char*)As + i*4096 + t*16);
    }
    const u16* bb = Vgb + ((size_t)((k0 + kt) >> 5) * 512 + nc*128) * 32;
    #pragma unroll
    for(int i = 0; i < 2; i++)
      gload16(bb + i*2048 + t*8, (char*)Bs + i*4096 + t*16);
    __syncthreads();
    f16x8 af[4], bfr[4];
    #pragma unroll
    for(int mi = 0; mi < 4; mi++)
      af[mi] = *(const f16x8*)((const char*)As + (wr + mi*16 + l15)*64 + l4*16);
    #pragma unroll
    for(int ni = 0; ni < 4; ni++)
      bfr[ni] = *(const f16x8*)((const char*)Bs + (wc + ni*16 + l15)*64 + l4*16);
    #pragma unroll
    for(int mi = 0; mi < 4; mi++)
      #pragma unroll
      for(int ni = 0; ni < 4; ni++)
        acc[mi][ni] = __builtin_amdgcn_mfma_f32_16x16x32_f16(af[mi], bfr[ni], acc[mi][ni], 0, 0, 0);
  }
  float* Cb = NVb + (size_t)(qt*128) * Cch + nc*128;
  #pragma unroll
  for(int mi = 0; mi < 4; mi++)
    #pragma unroll
    for(int ni = 0; ni < 4; ni++){
      int cl = wc + ni*16 + l15;
      #pragma unroll
      for(int r = 0; r < 4; r++){
        int rl = wr + mi*16 + l4*4 + r;
        atomicAdd(&Cb[(size_t)rl * Cch + cl], acc[mi][ni][r]);
      }
    }
}

// ---------------- V projection GEMM (BN=64), writes blocked f16 Vg ----------------
__global__ __launch_bounds__(256) void k_vproj(const u16* __restrict__ A,
                                               const u16* __restrict__ Bt,
                                               u16* __restrict__ Vg){
  __shared__ u16 As[4096], Bs[2048];
  const int bm = blockIdx.x * 128, bn = blockIdx.y * 64;
  f32x4 acc[4][2] = {};
  core_plain64(A + (size_t)bm*512, Bt + (size_t)bn*512, 512, 512, 512, As, Bs, acc);
  const int t = threadIdx.x, lane = t & 63, w = t >> 6;
  const int l15 = lane & 15, l4 = lane >> 4;
  const int wr = (w >> 1) * 64, wc = (w & 1) * 32;
  #pragma unroll
  for(int mi = 0; mi < 4; mi++)
    #pragma unroll
    for(int ni = 0; ni < 2; ni++){
      int col = bn + wc + ni*16 + l15;
      #pragma unroll
      for(int r = 0; r < 4; r++){
        int row = bm + wr + mi*16 + l4*4 + r;
        int b = row >> 12, tq = row & 4095;
        // Vg[b][tq>>5][col][tq&31]
        Vg[(size_t)b*Cch*Tt + ((size_t)(tq >> 5) * 512 + col) * 32 + (tq & 31)] = f2h(acc[mi][ni][r]);
      }
    }
}

// ---------------- FFN1: +bias, relu, bf16 out (BN=128) ----------------
__global__ __launch_bounds__(256) void k_ffn1(const u16* __restrict__ A,
                                              const u16* __restrict__ Bt,
                                              u16* __restrict__ Hout,
                                              const float* __restrict__ bias){
  __shared__ u16 As[4096], Bs[4096];
  const int bm = blockIdx.x * 128, bn = blockIdx.y * 128;
  f32x4 acc[4][4] = {};
  core_plain(A + (size_t)bm*512, Bt + (size_t)bn*512, 512, 512, 512, As, Bs, acc);
  const int t = threadIdx.x, lane = t & 63, w = t >> 6;
  const int l15 = lane & 15, l4 = lane >> 4;
  const int wr = (w >> 1) * 64, wc = (w & 1) * 64;
  #pragma unroll
  for(int mi = 0; mi < 4; mi++)
    #pragma unroll
    for(int ni = 0; ni < 4; ni++){
      int col = bn + wc + ni*16 + l15;
      float bv = bias[col];
      #pragma unroll
      for(int r = 0; r < 4; r++){
        int row = bm + wr + mi*16 + l4*4 + r;
        float v = acc[mi][ni][r] + bv;
        v = v > 0.f ? v : 0.f;
        Hout[(size_t)row * DFFd + col] = f2bf(v);
      }
    }
}

// ---------------- FFN2 (BN=64): +bias, f32 direct store ----------------
__global__ __launch_bounds__(256) void k_ffn2(const u16* __restrict__ A,
                                              const u16* __restrict__ Bt,
                                              float* __restrict__ out,
                                              const float* __restrict__ bias){
  __shared__ u16 As[4096], Bs[2048];
  const int bm = blockIdx.x * 128, bn = blockIdx.y * 64;
  f32x4 acc[4][2] = {};
  core_plain64(A + (size_t)bm*2048, Bt + (size_t)bn*2048, 2048, 2048, 2048, As, Bs, acc);
  const int t = threadIdx.x, lane = t & 63, w = t >> 6;
  const int l15 = lane & 15, l4 = lane >> 4;
  const int wr = (w >> 1) * 64, wc = (w & 1) * 32;
  #pragma unroll
  for(int mi = 0; mi < 4; mi++)
    #pragma unroll
    for(int ni = 0; ni < 2; ni++){
      int col = bn + wc + ni*16 + l15;
      float bv = bias[col];
      #pragma unroll
      for(int r = 0; r < 4; r++){
        int row = bm + wr + mi*16 + l4*4 + r;
        out[(size_t)row * Cch + col] = acc[mi][ni][r] + bv;
      }
    }
}

// ---------------- small utility kernels ----------------
__global__ void k_zero4(float* __restrict__ p, int n){
  int i = (blockIdx.x * blockDim.x + threadIdx.x) * 4;
  if(i < n) *(f32x4*)(p + i) = (f32x4){0.f,0.f,0.f,0.f};
}
__global__ void k_nv_final(const float* __restrict__ acc, u16* __restrict__ nv, int n){
  int i = (blockIdx.x * blockDim.x + threadIdx.x) * 4;
  if(i < n){
    f32x4 v = *(const f32x4*)(acc + i);
    us4 o; o.x = f2bf(v[0]); o.y = f2bf(v[1]); o.z = f2bf(v[2]); o.w = f2bf(v[3]);
    *(us4*)(nv + i) = o;
  }
}

// ---------------- launch ----------------
extern "C" void kernel_launch(void* const* d_in, const int* in_sizes, int n_in,
                              void* d_out, int out_size, void* d_ws, size_t ws_size,
                              hipStream_t stream){
  (void)in_sizes; (void)n_in; (void)out_size;
  const float* X  = (const float*)d_in[0];
  const float* Wq = (const float*)d_in[1];
  const float* Wk = (const float*)d_in[2];
  const float* Wv = (const float*)d_in[3];
  const float* W1 = (const float*)d_in[4];
  const float* b1 = (const float*)d_in[5];
  const float* W2 = (const float*)d_in[6];
  const float* b2 = (const float*)d_in[7];
  float* out = (float*)d_out;

  // Workspace layout (f16 panes, 16.5 MiB each):
  //   [0, nb*PANE_B)  S panes (overlap Xh[0,16M)+Xl[16M,32M) pre-attn; H[0,64M) at FFN)
  //   then QK(32M) | Vg(16M) | NVacc(32M) | NV(16M) | weights(6.5M) = 102.5 MiB tail
  // Peak: nb=4 -> 168.5 MiB (fits the ws that round 9 proved >= 169 MiB)
  const size_t MB = 1024ull*1024ull;
  const size_t PANE_B = (size_t)TRI * 2;   // 17,301,504 B
  char* ws = (char*)d_ws;

  int nb = 1;
  if(ws_size >= 4*PANE_B + 103*MB) nb = 4;
  else if(ws_size >= 2*PANE_B + 103*MB) nb = 2;

  u16*   Sp = (u16*)ws;
  u16*   Xh = (u16*)ws;
  u16*   Xl = (u16*)(ws + 16*MB);
  u16*   H  = (u16*)ws;
  size_t off = (size_t)nb * PANE_B;
  if(off < 32*MB) off = 32*MB;
  u16*   QK    = (u16*)(ws + off);  off += 32*MB;
  u16*   Vg    = (u16*)(ws + off);  off += 16*MB;
  float* NVacc = (float*)(ws + off); off += 32*MB;
  u16*   NV    = (u16*)(ws + off);  off += 16*MB;
  u16*   Wqkh  = (u16*)(ws + off);  off += 1*MB;
  u16*   Wqkl  = (u16*)(ws + off);  off += 1*MB;
  u16*   Wvt   = (u16*)(ws + off);  off += 1*MB;
  u16*   W1t   = (u16*)(ws + off);  off += 2*MB;
  u16*   W2t   = (u16*)(ws + off);

  dim3 tb(32, 8);

  // 1. split-cast X
  k_split_cast<<<Mrows*Cch/4/256, 256, 0, stream>>>(X, Xh, Xl, Mrows*Cch);

  // 2. weight transposes (Wq/Wk split, Wv/W1/W2 plain)
  k_transpose_split<<<dim3(16,16), tb, 0, stream>>>(Wq, Wqkh,           Wqkl,           512, 512);
  k_transpose_split<<<dim3(16,16), tb, 0, stream>>>(Wk, Wqkh + 512*512, Wqkl + 512*512, 512, 512);
  k_transpose_f32_bf16<<<dim3(16,16), tb, 0, stream>>>(Wv, Wvt, 512, 512);
  k_transpose_f32_bf16<<<dim3(64,16), tb, 0, stream>>>(W1, W1t, 2048, 512);
  k_transpose_f32_bf16<<<dim3(16,64), tb, 0, stream>>>(W2, W2t, 512, 2048);

  // 3. QK projection (split-bf16 compute, f16 store); V projection -> blocked f16 Vg
  k_qk_split<<<dim3(128, 8), 256, 0, stream>>>(Xh, Xl, Wqkh, Wqkl, QK);
  k_vproj<<<dim3(128, 8), 256, 0, stream>>>(Xh, Wvt, Vg);

  // 4. attention: nb batches per pass (longest-first), f16 S/P, f16 PV
  k_zero4<<<Mrows*Cch/4/256, 256, 0, stream>>>(NVacc, Mrows*Cch);
  for(int b0 = 0; b0 < Bb; b0 += nb){
    k_score<<<dim3(32, 32, nb), 256, 0, stream>>>(QK, b0, Sp);
    k_softmax<<<dim3(1024, 1, nb), 256, 0, stream>>>(Sp);
    k_pv<<<dim3(4, 32, 4*nb), 256, 0, stream>>>(Sp, Vg, NVacc, b0);
  }
  k_nv_final<<<Mrows*Cch/4/256, 256, 0, stream>>>(NVacc, NV, Mrows*Cch);

  // 5. FFN (FFN1 BN=128; FFN2 BN=64 direct store)
  k_ffn1<<<dim3(128, 16), 256, 0, stream>>>(NV, W1t, H, b1);
  k_ffn2<<<dim3(128, 8), 256, 0, stream>>>(H, W2t, out, b2);
}

// Round 11
// 382.991 us; speedup vs baseline: 1.7103x; 1.0667x over previous
//
#include <hip/hip_runtime.h>
#include <stdint.h>

typedef __attribute__((ext_vector_type(8))) short bf16x8;
typedef __attribute__((ext_vector_type(8))) _Float16 f16x8;
typedef __attribute__((ext_vector_type(4))) float f32x4;
typedef __attribute__((ext_vector_type(4))) unsigned short us4;
typedef unsigned short u16;

#define DEVI static __device__ __forceinline__

#define Bb 4
#define Tt 4096
#define Cch 512
#define DFFd 2048
#define Mrows (Bb*Tt)
#define TRI 8650752ull   // u16 elements per packed causal pane = PANE(32)

DEVI u16 f2bf(float f){
  union{float f;unsigned u;} v; v.f = f;
  unsigned r = v.u + 0x7FFFu + ((v.u >> 16) & 1u);
  return (u16)(r >> 16);
}
DEVI u16 f2h(float f){
  union{_Float16 h; u16 u;} v; v.h = (_Float16)f; return v.u;
}
DEVI float h2f(u16 h){
  union{u16 u; _Float16 h;} v; v.u = h; return (float)v.h;
}
// packed-triangular pane offset (u16 elements): sum_{j<q}(j+1)*128*128
DEVI size_t PANE(int q){ return (size_t)8192 * (size_t)(q*(q+1)); }

DEVI void gload16(const void* g, void* l){
  __builtin_amdgcn_global_load_lds((const __attribute__((address_space(1))) unsigned int*)g,
                                   (__attribute__((address_space(3))) unsigned int*)l, 16, 0, 0);
}

// ---------------- cast f32 -> f16 ----------------
__global__ void k_cast_f16(const float* __restrict__ in, u16* __restrict__ out, int n){
  int i = (blockIdx.x * blockDim.x + threadIdx.x) * 4;
  if(i < n){
    float4 f = *(const float4*)(in + i);
    us4 o; o.x = f2h(f.x); o.y = f2h(f.y); o.z = f2h(f.z); o.w = f2h(f.w);
    *(us4*)(out + i) = o;
  }
}

// ------------- transpose-cast f32 -> f16 -------------
__global__ void k_transpose_f32_f16(const float* __restrict__ in, u16* __restrict__ out,
                                    int inStride, int outStride){
  __shared__ float tile[32][33];
  int c0 = blockIdx.x * 32, r0 = blockIdx.y * 32;
  int tx = threadIdx.x, ty = threadIdx.y; // (32,8)
  #pragma unroll
  for(int j = 0; j < 4; j++)
    tile[ty + 8*j][tx] = in[(size_t)(r0 + ty + 8*j) * inStride + c0 + tx];
  __syncthreads();
  #pragma unroll
  for(int j = 0; j < 4; j++)
    out[(size_t)(c0 + ty + 8*j) * outStride + r0 + tx] = f2h(tile[tx][ty + 8*j]);
}

// ------------- transpose-cast f32 -> bf16 -------------
__global__ void k_transpose_f32_bf16(const float* __restrict__ in, u16* __restrict__ out,
                                     int inStride, int outStride){
  __shared__ float tile[32][33];
  int c0 = blockIdx.x * 32, r0 = blockIdx.y * 32;
  int tx = threadIdx.x, ty = threadIdx.y;
  #pragma unroll
  for(int j = 0; j < 4; j++)
    tile[ty + 8*j][tx] = in[(size_t)(r0 + ty + 8*j) * inStride + c0 + tx];
  __syncthreads();
  #pragma unroll
  for(int j = 0; j < 4; j++)
    out[(size_t)(c0 + ty + 8*j) * outStride + r0 + tx] = f2bf(tile[tx][ty + 8*j]);
}

// ---------------- f16 GEMM core (single MFMA, BN=128) ----------------
DEVI void core_f16(const u16* __restrict__ A, const u16* __restrict__ B,
                   int lda, int ldb, int K, u16* As, u16* Bs, f32x4 (&acc)[4][4]){
  const int t = threadIdx.x;
  const int lane = t & 63, w = t >> 6;
  const int l15 = lane & 15, l4 = lane >> 4;
  const int wr = (w >> 1) * 64, wc = (w & 1) * 64;
  for(int kt = 0; kt < K; kt += 32){
    __syncthreads();
    #pragma unroll
    for(int i = 0; i < 2; i++){
      int row = i*64 + (t >> 2);
      int ce  = (t & 3) * 8;
      gload16(A + (size_t)row * lda + kt + ce, (char*)As + i*4096 + t*16);
      gload16(B + (size_t)row * ldb + kt + ce, (char*)Bs + i*4096 + t*16);
    }
    __syncthreads();
    f16x8 af[4], bfr[4];
    #pragma unroll
    for(int mi = 0; mi < 4; mi++)
      af[mi] = *(const f16x8*)((const char*)As + (wr + mi*16 + l15)*64 + l4*16);
    #pragma unroll
    for(int ni = 0; ni < 4; ni++)
      bfr[ni] = *(const f16x8*)((const char*)Bs + (wc + ni*16 + l15)*64 + l4*16);
    #pragma unroll
    for(int mi = 0; mi < 4; mi++)
      #pragma unroll
      for(int ni = 0; ni < 4; ni++)
        acc[mi][ni] = __builtin_amdgcn_mfma_f32_16x16x32_f16(af[mi], bfr[ni], acc[mi][ni], 0, 0, 0);
  }
}

// ---------------- fused QKV projection (f16): cols<1024 -> QK, cols>=1024 -> blocked Vg ----------------
__global__ __launch_bounds__(256) void k_qkv(const u16* __restrict__ Xf,
                                             const u16* __restrict__ Wt,
                                             u16* __restrict__ QK,
                                             u16* __restrict__ Vg){
  __shared__ u16 As[4096], Bs[4096];
  const int bm = blockIdx.x * 128, bn = blockIdx.y * 128;
  f32x4 acc[4][4] = {};
  core_f16(Xf + (size_t)bm*512, Wt + (size_t)bn*512, 512, 512, 512, As, Bs, acc);
  const int t = threadIdx.x, lane = t & 63, w = t >> 6;
  const int l15 = lane & 15, l4 = lane >> 4;
  const int wr = (w >> 1) * 64, wc = (w & 1) * 64;
  #pragma unroll
  for(int mi = 0; mi < 4; mi++)
    #pragma unroll
    for(int ni = 0; ni < 4; ni++){
      int col = bn + wc + ni*16 + l15;
      #pragma unroll
      for(int r = 0; r < 4; r++){
        int row = bm + wr + mi*16 + l4*4 + r;
        u16 h = f2h(acc[mi][ni][r]);
        if(col < 1024){
          QK[(size_t)row * 1024 + col] = h;
        } else {
          int c = col - 1024;
          int b = row >> 12, tq = row & 4095;
          Vg[(size_t)b*Cch*Tt + ((size_t)(tq >> 5) * 512 + c) * 32 + (tq & 31)] = h;
        }
      }
    }
}

// ---------------- causal score GEMM: grid (32,32,nb); qt descending; f16 packed out ----------------
__global__ __launch_bounds__(256) void k_score(const u16* __restrict__ QK, int b0,
                                               u16* __restrict__ Sp){
  const int kt = blockIdx.x, qt = 31 - blockIdx.y;
  if(kt > qt) return;
  const int zb = blockIdx.z;
  const u16* QKb = QK + (size_t)(b0 + zb) * Tt * 1024;
  u16* Spz = Sp + (size_t)zb * TRI;
  __shared__ u16 As[4096], Bs[4096];
  const u16* A = QKb + (size_t)(qt*128) * 1024;        // q rows
  const u16* B = QKb + (size_t)(kt*128) * 1024 + 512;  // k rows
  f32x4 acc[4][4] = {};
  core_f16(A, B, 1024, 1024, 512, As, Bs, acc);
  const int t = threadIdx.x, lane = t & 63, w = t >> 6;
  const int l15 = lane & 15, l4 = lane >> 4;
  const int wr = (w >> 1) * 64, wc = (w & 1) * 64;
  const int ldc = (qt + 1) * 128;
  u16* C = Spz + PANE(qt) + (size_t)kt*128;
  const bool diag = (kt == qt);
  #pragma unroll
  for(int mi = 0; mi < 4; mi++)
    #pragma unroll
    for(int ni = 0; ni < 4; ni++){
      int cl = wc + ni*16 + l15;
      #pragma unroll
      for(int r = 0; r < 4; r++){
        int rl = wr + mi*16 + l4*4 + r;
        float v = acc[mi][ni][r];
        if(diag && cl > rl) v = -__builtin_inff();
        C[(size_t)rl * ldc + cl] = f2h(v);
      }
    }
}

// ---------------- softmax: wave per row; f16 S -> normalized f16 P in place ----------------
__global__ __launch_bounds__(256) void k_softmax(u16* __restrict__ Sp){
  u16* Spz = Sp + (size_t)blockIdx.z * TRI;
  const int w = threadIdx.x >> 6, lane = threadIdx.x & 63;
  const int r = (1023 - blockIdx.x) * 4 + w;  // 0..4095, descending qt
  const int qt = r >> 7;
  const int nc = qt + 1;                      // chunks of 128 u16 (ushort2/lane)
  const int L = nc * 128;
  const size_t base = PANE(qt) + (size_t)(r & 127) * L;
  ushort2* rp = (ushort2*)(Spz + base);
  float2 v[32];
  float mx = -__builtin_inff();
  #pragma unroll
  for(int c = 0; c < 32; c++) if(c < nc){
    ushort2 h = rp[c*64 + lane];
    v[c].x = h2f(h.x); v[c].y = h2f(h.y);
    mx = fmaxf(mx, fmaxf(v[c].x, v[c].y));
  }
  #pragma unroll
  for(int s = 1; s < 64; s <<= 1) mx = fmaxf(mx, __shfl_xor(mx, s));
  float sm = 0.f;
  #pragma unroll
  for(int c = 0; c < 32; c++) if(c < nc){
    v[c].x = __expf(v[c].x - mx);
    v[c].y = __expf(v[c].y - mx);
    sm += v[c].x + v[c].y;
  }
  #pragma unroll
  for(int s = 1; s < 64; s <<= 1) sm += __shfl_xor(sm, s);
  const float inv = 1.f / sm;
  #pragma unroll
  for(int c = 0; c < 32; c++) if(c < nc){
    ushort2 o; o.x = f2h(v[c].x * inv); o.y = f2h(v[c].y * inv);
    rp[c*64 + lane] = o;
  }
}

// ---------------- PV GEMM (f16, full-L per block, no atomics): direct bf16 NV store ----------------
__global__ __launch_bounds__(256) void k_pv(const u16* __restrict__ Pp, const u16* __restrict__ Vg,
                                            u16* __restrict__ NV, int b0){
  const int nc = blockIdx.x, qt = 31 - blockIdx.y, zb = blockIdx.z;
  const int L = (qt + 1) * 128;
  __shared__ u16 As[4096], Bs[4096];
  const u16* A = Pp + (size_t)zb * TRI + PANE(qt);             // f16 P, row stride L
  const u16* Vgb = Vg + (size_t)(b0 + zb) * Cch * Tt;          // blocked [t/32][c][t%32] f16
  const int t = threadIdx.x, lane = t & 63, w = t >> 6;
  const int l15 = lane & 15, l4 = lane >> 4;
  const int wr = (w >> 1) * 64, wc = (w & 1) * 64;
  f32x4 acc[4][4] = {};
  for(int kt = 0; kt < L; kt += 32){
    __syncthreads();
    #pragma unroll
    for(int i = 0; i < 2; i++){
      int row = i*64 + (t >> 2);
      int ce  = (t & 3) * 8;
      gload16(A + (size_t)row * L + kt + ce, (char*)As + i*4096 + t*16);
    }
    const u16* bb = Vgb + ((size_t)(kt >> 5) * 512 + nc*128) * 32;
    #pragma unroll
    for(int i = 0; i < 2; i++)
      gload16(bb + i*2048 + t*8, (char*)Bs + i*4096 + t*16);
    __syncthreads();
    f16x8 af[4], bfr[4];
    #pragma unroll
    for(int mi = 0; mi < 4; mi++)
      af[mi] = *(const f16x8*)((const char*)As + (wr + mi*16 + l15)*64 + l4*16);
    #pragma unroll
    for(int ni = 0; ni < 4; ni++)
      bfr[ni] = *(const f16x8*)((const char*)Bs + (wc + ni*16 + l15)*64 + l4*16);
    #pragma unroll
    for(int mi = 0; mi < 4; mi++)
      #pragma unroll
      for(int ni = 0; ni < 4; ni++)
        acc[mi][ni] = __builtin_amdgcn_mfma_f32_16x16x32_f16(af[mi], bfr[ni], acc[mi][ni], 0, 0, 0);
  }
  u16* Cb = NV + ((size_t)(b0 + zb) * Tt + qt*128) * Cch + nc*128;
  #pragma unroll
  for(int mi = 0; mi < 4; mi++)
    #pragma unroll
    for(int ni = 0; ni < 4; ni++){
      int cl = wc + ni*16 + l15;
      #pragma unroll
      for(int r = 0; r < 4; r++){
        int rl = wr + mi*16 + l4*4 + r;
        Cb[(size_t)rl * Cch + cl] = f2bf(acc[mi][ni][r]);
      }
    }
}

// ---------------- plain bf16 GEMM core (BN=128) ----------------
DEVI void core_plain(const u16* __restrict__ A, const u16* __restrict__ B,
                     int lda, int ldb, int K, u16* As, u16* Bs, f32x4 (&acc)[4][4]){
  const int t = threadIdx.x;
  const int lane = t & 63, w = t >> 6;
  const int l15 = lane & 15, l4 = lane >> 4;
  const int wr = (w >> 1) * 64, wc = (w & 1) * 64;
  for(int kt = 0; kt < K; kt += 32){
    __syncthreads();
    #pragma unroll
    for(int i = 0; i < 2; i++){
      int row = i*64 + (t >> 2);
      int ce  = (t & 3) * 8;
      gload16(A + (size_t)row * lda + kt + ce, (char*)As + i*4096 + t*16);
      gload16(B + (size_t)row * ldb + kt + ce, (char*)Bs + i*4096 + t*16);
    }
    __syncthreads();
    bf16x8 af[4], bfr[4];
    #pragma unroll
    for(int mi = 0; mi < 4; mi++)
      af[mi] = *(const bf16x8*)((const char*)As + (wr + mi*16 + l15)*64 + l4*16);
    #pragma unroll
    for(int ni = 0; ni < 4; ni++)
      bfr[ni] = *(const bf16x8*)((const char*)Bs + (wc + ni*16 + l15)*64 + l4*16);
    #pragma unroll
    for(int mi = 0; mi < 4; mi++)
      #pragma unroll
      for(int ni = 0; ni < 4; ni++)
        acc[mi][ni] = __builtin_amdgcn_mfma_f32_16x16x32_bf16(af[mi], bfr[ni], acc[mi][ni], 0, 0, 0);
  }
}

// ---------------- plain bf16 GEMM core, BN=64 ----------------
DEVI void core_plain64(const u16* __restrict__ A, const u16* __restrict__ B,
                       int lda, int ldb, int K, u16* As, u16* Bs, f32x4 (&acc)[4][2]){
  const int t = threadIdx.x;
  const int lane = t & 63, w = t >> 6;
  const int l15 = lane & 15, l4 = lane >> 4;
  const int wr = (w >> 1) * 64, wc = (w & 1) * 32;
  for(int kt = 0; kt < K; kt += 32){
    __syncthreads();
    #pragma unroll
    for(int i = 0; i < 2; i++){
      int row = i*64 + (t >> 2);
      int ce  = (t & 3) * 8;
      gload16(A + (size_t)row * lda + kt + ce, (char*)As + i*4096 + t*16);
    }
    {
      int row = t >> 2;
      int ce  = (t & 3) * 8;
      gload16(B + (size_t)row * ldb + kt + ce, (char*)Bs + t*16);
    }
    __syncthreads();
    bf16x8 af[4], bfr[2];
    #pragma unroll
    for(int mi = 0; mi < 4; mi++)
      af[mi] = *(const bf16x8*)((const char*)As + (wr + mi*16 + l15)*64 + l4*16);
    #pragma unroll
    for(int ni = 0; ni < 2; ni++)
      bfr[ni] = *(const bf16x8*)((const char*)Bs + (wc + ni*16 + l15)*64 + l4*16);
    #pragma unroll
    for(int mi = 0; mi < 4; mi++)
      #pragma unroll
      for(int ni = 0; ni < 2; ni++)
        acc[mi][ni] = __builtin_amdgcn_mfma_f32_16x16x32_bf16(af[mi], bfr[ni], acc[mi][ni], 0, 0, 0);
  }
}

// ---------------- FFN1: +bias, relu, bf16 out (BN=128) ----------------
__global__ __launch_bounds__(256) void k_ffn1(const u16* __restrict__ A,
                                              const u16* __restrict__ Bt,
                                              u16* __restrict__ Hout,
                                              const float* __restrict__ bias){
  __shared__ u16 As[4096], Bs[4096];
  const int bm = blockIdx.x * 128, bn = blockIdx.y * 128;
  f32x4 acc[4][4] = {};
  core_plain(A + (size_t)bm*512, Bt + (size_t)bn*512, 512, 512, 512, As, Bs, acc);
  const int t = threadIdx.x, lane = t & 63, w = t >> 6;
  const int l15 = lane & 15, l4 = lane >> 4;
  const int wr = (w >> 1) * 64, wc = (w & 1) * 64;
  #pragma unroll
  for(int mi = 0; mi < 4; mi++)
    #pragma unroll
    for(int ni = 0; ni < 4; ni++){
      int col = bn + wc + ni*16 + l15;
      float bv = bias[col];
      #pragma unroll
      for(int r = 0; r < 4; r++){
        int row = bm + wr + mi*16 + l4*4 + r;
        float v = acc[mi][ni][r] + bv;
        v = v > 0.f ? v : 0.f;
        Hout[(size_t)row * DFFd + col] = f2bf(v);
      }
    }
}

// ---------------- FFN2 (BN=64): +bias, f32 direct store ----------------
__global__ __launch_bounds__(256) void k_ffn2(const u16* __restrict__ A,
                                              const u16* __restrict__ Bt,
                                              float* __restrict__ out,
                                              const float* __restrict__ bias){
  __shared__ u16 As[4096], Bs[2048];
  const int bm = blockIdx.x * 128, bn = blockIdx.y * 64;
  f32x4 acc[4][2] = {};
  core_plain64(A + (size_t)bm*2048, Bt + (size_t)bn*2048, 2048, 2048, 2048, As, Bs, acc);
  const int t = threadIdx.x, lane = t & 63, w = t >> 6;
  const int l15 = lane & 15, l4 = lane >> 4;
  const int wr = (w >> 1) * 64, wc = (w & 1) * 32;
  #pragma unroll
  for(int mi = 0; mi < 4; mi++)
    #pragma unroll
    for(int ni = 0; ni < 2; ni++){
      int col = bn + wc + ni*16 + l15;
      float bv = bias[col];
      #pragma unroll
      for(int r = 0; r < 4; r++){
        int row = bm + wr + mi*16 + l4*4 + r;
        out[(size_t)row * Cch + col] = acc[mi][ni][r] + bv;
      }
    }
}

// ---------------- launch ----------------
extern "C" void kernel_launch(void* const* d_in, const int* in_sizes, int n_in,
                              void* d_out, int out_size, void* d_ws, size_t ws_size,
                              hipStream_t stream){
  (void)in_sizes; (void)n_in; (void)out_size;
  const float* X  = (const float*)d_in[0];
  const float* Wq = (const float*)d_in[1];
  const float* Wk = (const float*)d_in[2];
  const float* Wv = (const float*)d_in[3];
  const float* W1 = (const float*)d_in[4];
  const float* b1 = (const float*)d_in[5];
  const float* W2 = (const float*)d_in[6];
  const float* b2 = (const float*)d_in[7];
  float* out = (float*)d_out;

  // Workspace layout (f16 panes, 16.5 MiB each):
  //   [0, nb*PANE_B)  S panes (overlap Xf[0,16M) pre-attn; H[0,64M) at FFN)
  //   then QK(32M) | Vg(16M) | NV(16M) | weights(5.5M)
  // Peak: nb=4 -> 136.5 MiB
  const size_t MB = 1024ull*1024ull;
  const size_t PANE_B = (size_t)TRI * 2;   // 17,301,504 B
  char* ws = (char*)d_ws;

  int nb = 1;
  if(ws_size >= 4*PANE_B + 71*MB) nb = 4;
  else if(ws_size >= 2*PANE_B + 71*MB) nb = 2;

  u16*   Sp = (u16*)ws;
  u16*   Xf = (u16*)ws;
  u16*   H  = (u16*)ws;
  size_t off = (size_t)nb * PANE_B;
  u16*   QK   = (u16*)(ws + off);  off += 32*MB;
  u16*   Vg   = (u16*)(ws + off);  off += 16*MB;
  u16*   NV   = (u16*)(ws + off);  off += 16*MB;
  u16*   Wt   = (u16*)(ws + off);  off += 2*MB;   // [1536][512] f16 (1.5M used)
  u16*   W1t  = (u16*)(ws + off);  off += 2*MB;
  u16*   W2t  = (u16*)(ws + off);

  dim3 tb(32, 8);

  // 1. cast X -> f16
  k_cast_f16<<<Mrows*Cch/4/256, 256, 0, stream>>>(X, Xf, Mrows*Cch);

  // 2. weight transposes: Wq/Wk/Wv -> f16 Wt rows; W1/W2 -> bf16
  k_transpose_f32_f16<<<dim3(16,16), tb, 0, stream>>>(Wq, Wt,            512, 512);
  k_transpose_f32_f16<<<dim3(16,16), tb, 0, stream>>>(Wk, Wt +  512*512, 512, 512);
  k_transpose_f32_f16<<<dim3(16,16), tb, 0, stream>>>(Wv, Wt + 1024*512, 512, 512);
  k_transpose_f32_bf16<<<dim3(64,16), tb, 0, stream>>>(W1, W1t, 2048, 512);
  k_transpose_f32_bf16<<<dim3(16,64), tb, 0, stream>>>(W2, W2t, 512, 2048);

  // 3. fused QKV projection (f16): QK layout + blocked Vg
  k_qkv<<<dim3(128, 12), 256, 0, stream>>>(Xf, Wt, QK, Vg);

  // 4. attention: nb batches per pass (longest-first), f16 S/P, f16 PV, direct bf16 NV
  for(int b0 = 0; b0 < Bb; b0 += nb){
    k_score<<<dim3(32, 32, nb), 256, 0, stream>>>(QK, b0, Sp);
    k_softmax<<<dim3(1024, 1, nb), 256, 0, stream>>>(Sp);
    k_pv<<<dim3(4, 32, nb), 256, 0, stream>>>(Sp, Vg, NV, b0);
  }

  // 5. FFN (FFN1 BN=128; FFN2 BN=64 direct store)
  k_ffn1<<<dim3(128, 16), 256, 0, stream>>>(NV, W1t, H, b1);
  k_ffn2<<<dim3(128, 8), 256, 0, stream>>>(H, W2t, out, b2);
}